// Round 7
// baseline (381.312 us; speedup 1.0000x reference)
//
#include <hip/hip_runtime.h>

#define NBATCH 4
#define NS 2048
#define ND 1024
#define NH 8
#define HD 128
#define NFF 512
#define NE 8
#define NT 65536       /* B*S*H tokens */
#define NBS 8192       /* B*S rows */
#define MU_F 0.7f
#define LN_EPS_F 1e-5f

typedef __attribute__((ext_vector_type(4))) float f32x4;
typedef __attribute__((ext_vector_type(2))) double f64x2;
typedef __attribute__((ext_vector_type(8))) _Float16 f16x8;
typedef __attribute__((ext_vector_type(4))) _Float16 f16x4;
typedef __attribute__((ext_vector_type(2))) _Float16 f16x2;

__device__ __forceinline__ void gload_lds16(const void* g, void* l) {
  __builtin_amdgcn_global_load_lds(
      (const __attribute__((address_space(1))) unsigned int*)g,
      (__attribute__((address_space(3))) unsigned int*)l, 16, 0, 0);
}

// cnt is strided: cnt[e*64] so the 8 counters live in different cache lines/TCC channels
__global__ void zero_cnt_kernel(int* cnt) {
  cnt[threadIdx.x] = 0;
}

// plain fp32 -> fp16 convert, 4 elems/thread
__global__ void cvt_f16_kernel(const float* __restrict__ in, _Float16* __restrict__ out, int n4) {
  int i = blockIdx.x * blockDim.x + threadIdx.x;
  if (i >= n4) return;
  float4 v = ((const float4*)in)[i];
  f16x4 h = { (_Float16)v.x, (_Float16)v.y, (_Float16)v.z, (_Float16)v.w };
  *(f16x4*)(out + (size_t)i * 4) = h;
}

// batched transpose + convert: in [batch][R][C] f32 -> out [batch][C][R] f16
// R, C multiples of 32. block (32,8), grid (C/32, R/32, batch)
__global__ void tr_cvt_kernel(const float* __restrict__ in, _Float16* __restrict__ out, int R, int C) {
  __shared__ float tile[32][33];
  int b = blockIdx.z;
  const float* inp = in + (size_t)b * R * C;
  _Float16* outp = out + (size_t)b * R * C;
  int c = blockIdx.x * 32 + threadIdx.x;
  int r0 = blockIdx.y * 32;
  #pragma unroll
  for (int i = 0; i < 4; i++) {
    int r = r0 + threadIdx.y + i * 8;
    tile[threadIdx.y + i * 8][threadIdx.x] = inp[(size_t)r * C + c];
  }
  __syncthreads();
  int rr = r0 + threadIdx.x;
  #pragma unroll
  for (int i = 0; i < 4; i++) {
    int cc = blockIdx.x * 32 + threadIdx.y + i * 8;
    outp[(size_t)cc * R + rr] = (_Float16)tile[threadIdx.x][threadIdx.y + i * 8];
  }
}

// G[d][o] (o = h*8+e) = sum_j split_W[d][h*128+j] * gate_W[j][e]  (fp64)
// gbias[o] = split_b[h*128:] . gate_W[:,e] + gate_b[e]
__global__ void build_G_kernel(const float* __restrict__ split_W, const float* __restrict__ split_b,
                               const float* __restrict__ gate_W, const float* __restrict__ gate_b,
                               double* __restrict__ G, double* __restrict__ gbias) {
  int idx = blockIdx.x * 256 + threadIdx.x;   // 65536 total
  int d = idx >> 6, o = idx & 63, h = o >> 3, e = o & 7;
  double acc = 0.0;
  for (int j = 0; j < 128; j++)
    acc += (double)split_W[(size_t)d * ND + h * 128 + j] * (double)gate_W[j * 8 + e];
  G[idx] = acc;
  if (idx < 64) {
    double bacc = 0.0;
    for (int j = 0; j < 128; j++)
      bacc += (double)split_b[h * 128 + j] * (double)gate_W[j * 8 + e];
    gbias[idx] = bacc + (double)gate_b[e];
  }
}

// fp64 logits = x @ G + gbias, top-2 per (row,h), softmax, per-expert lists.
// v4: LDS fp64 mini-GEMM (conflict-free Gsx[kp][col] f64x2 layout) +
// hierarchical atomics (LDS counts -> 8 strided global atomics/block).
__global__ __launch_bounds__(256) void gate_kernel(const float* __restrict__ x,
    const double* __restrict__ G, const double* __restrict__ gbias,
    float* __restrict__ tkw, int* __restrict__ lists, int* __restrict__ cnt) {
  __shared__ f64x2 Gsx[32 * 64];     // 32 KB, [kp][col]
  __shared__ double xsd[16][66];     // 8.25 KB
  __shared__ double lg[16 * 64];     // 8 KB
  __shared__ int lcnt[8];
  __shared__ int lbase[8];
  int tid = threadIdx.x, lane = tid & 63, w = tid >> 6;
  int bs0 = blockIdx.x * 16;
  double acc[4];
  #pragma unroll
  for (int r = 0; r < 4; r++) acc[r] = 0.0;
  int xrow = tid >> 4, xc4 = tid & 15;
  const double* xr = &xsd[0][0] + (w * 4) * 66;
  if (tid < 8) lcnt[tid] = 0;

  for (int ch = 0; ch < 16; ch++) {
    __syncthreads();           // previous chunk's reads complete before overwrite
    float4 xv4 = *(const float4*)(x + (size_t)(bs0 + xrow) * ND + ch * 64 + xc4 * 4);
    f64x2 xa = { (double)xv4.x, (double)xv4.y };
    f64x2 xb = { (double)xv4.z, (double)xv4.w };
    *(f64x2*)&xsd[xrow][xc4 * 4]     = xa;
    *(f64x2*)&xsd[xrow][xc4 * 4 + 2] = xb;
    #pragma unroll
    for (int i = 0; i < 8; i++) {
      int idx = i * 256 + tid, kp = idx >> 6, c = idx & 63;
      const double* gp = G + (size_t)(ch * 64 + kp * 2) * 64 + c;
      f64x2 gv = { gp[0], gp[64] };
      Gsx[idx] = gv;
    }
    __syncthreads();
    #pragma unroll 4
    for (int kp = 0; kp < 32; kp++) {
      f64x2 g = Gsx[kp * 64 + lane];       // contiguous 16B/lane: conflict-free
      #pragma unroll
      for (int r = 0; r < 4; r++) {
        f64x2 xv = *(const f64x2*)(xr + r * 66 + kp * 2);   // broadcast
        acc[r] += xv.x * g.x;
        acc[r] += xv.y * g.y;
      }
    }
  }
  double gb = gbias[lane];
  #pragma unroll
  for (int r = 0; r < 4; r++)
    lg[(w * 4 + r) * 64 + lane] = acc[r] + gb;
  __syncthreads();

  int i1 = 0, i2 = 0, token = 0, p1 = 0, p2 = 0;
  if (tid < 128) {
    int row = tid >> 3, h = tid & 7;
    const double* L = lg + row * 64 + h * 8;
    double v1 = L[0];
    #pragma unroll
    for (int e2 = 1; e2 < 8; e2++) if (L[e2] > v1) { v1 = L[e2]; i1 = e2; }
    i2 = -1; double v2 = -1e300;
    #pragma unroll
    for (int e2 = 0; e2 < 8; e2++) if (e2 != i1 && L[e2] > v2) { v2 = L[e2]; i2 = e2; }
    float ex = expf((float)(v2 - v1));        // <= 1
    float den = 1.f + ex;
    float g1 = 1.f / den, g2 = ex / den;
    token = (bs0 + row) * 8 + h;
    tkw[token * 2]     = g1;
    tkw[token * 2 + 1] = g2;
    p1 = atomicAdd(&lcnt[i1], 1);             // LDS atomics: cheap
    p2 = atomicAdd(&lcnt[i2], 1);
  }
  __syncthreads();
  if (tid < 8) lbase[tid] = atomicAdd(cnt + tid * 64, lcnt[tid]);   // 8 global atomics/block
  __syncthreads();
  if (tid < 128) {
    lists[(size_t)i1 * NT + lbase[i1] + p1] = token * 2;
    lists[(size_t)i2 * NT + lbase[i2] + p2] = token * 2 + 1;
  }
}

// C[M][N] = A[M][K] @ Bt[N][K]^T + bias; fp16 inputs, fp32 acc.
// 128x128 tile, BK=32, 4 waves (2x2 of 64x64), global_load_lds width 16.
__global__ __launch_bounds__(256) void gemm_f16_kernel(
    const _Float16* __restrict__ A, const _Float16* __restrict__ Bt,
    const float* __restrict__ bias, float* __restrict__ Cf, _Float16* __restrict__ Ch,
    int M, int N, int Kd) {
  __shared__ _Float16 As[128 * 32];
  __shared__ _Float16 Bs[128 * 32];
  int tid = threadIdx.x, lane = tid & 63, w = tid >> 6;
  int wr = w >> 1, wc = w & 1;
  int m0 = blockIdx.y * 128, n0 = blockIdx.x * 128;
  f32x4 acc[4][4];
  #pragma unroll
  for (int i = 0; i < 4; i++)
    #pragma unroll
    for (int j = 0; j < 4; j++) acc[i][j] = (f32x4){0.f, 0.f, 0.f, 0.f};
  int srow = lane >> 2, scol = (lane & 3) * 8;
  int fr = lane & 15, ko = (lane >> 4) * 8;
  const _Float16* Ag = A + (size_t)(m0 + srow) * Kd + scol;
  const _Float16* Bg = Bt + (size_t)(n0 + srow) * Kd + scol;

  for (int k0 = 0; k0 < Kd; k0 += 32) {
    #pragma unroll
    for (int j = 0; j < 2; j++) {
      int rb = (w * 2 + j) * 16;
      gload_lds16(Ag + (size_t)rb * Kd + k0, As + rb * 32);
      gload_lds16(Bg + (size_t)rb * Kd + k0, Bs + rb * 32);
    }
    __syncthreads();
    f16x8 af[4], bq[4];
    #pragma unroll
    for (int mi = 0; mi < 4; mi++) af[mi] = *(const f16x8*)(As + (wr * 64 + mi * 16 + fr) * 32 + ko);
    #pragma unroll
    for (int ni = 0; ni < 4; ni++) bq[ni] = *(const f16x8*)(Bs + (wc * 64 + ni * 16 + fr) * 32 + ko);
    __syncthreads();
    #pragma unroll
    for (int mi = 0; mi < 4; mi++)
      #pragma unroll
      for (int ni = 0; ni < 4; ni++)
        acc[mi][ni] = __builtin_amdgcn_mfma_f32_16x16x32_f16(af[mi], bq[ni], acc[mi][ni], 0, 0, 0);
  }
  int rbase = m0 + wr * 64 + ((lane >> 4) << 2);
  int cbase = n0 + wc * 64 + (lane & 15);
  #pragma unroll
  for (int mi = 0; mi < 4; mi++)
    #pragma unroll
    for (int ni = 0; ni < 4; ni++) {
      int cc = cbase + ni * 16;
      float bv = bias ? bias[cc] : 0.f;
      #pragma unroll
      for (int r = 0; r < 4; r++) {
        int rr = rbase + mi * 16 + r;
        float v = acc[mi][ni][r] + bv;
        if (Cf) Cf[(size_t)rr * N + cc] = v;
        if (Ch) Ch[(size_t)rr * N + cc] = (_Float16)v;
      }
    }
}

// Grouped expert kernel v4: 64-ff chunks -> LDS 49 KB -> 2 blocks/CU (cross-block
// overlap of barrier/stage drains). Swizzle keyed ((row>>2)&3)<<5 on BOTH sides
// (write XOR index = g: 4 disjoint granule-pairs, conflict-free; read XOR index =
// fr>>2: balanced b128). Fixed buffer roles: Wb1=W1 chunk, Wb2=W2 chunk, each
// phase stages the other buffer's next chunk under compute. t in registers.
__global__ __launch_bounds__(512, 4) void expert_kernel(
    const _Float16* __restrict__ t_h, const _Float16* __restrict__ W1t, const _Float16* __restrict__ W2t,
    const float* __restrict__ b1, const float* __restrict__ b2,
    const int* __restrict__ cnt, const int* __restrict__ lists, const float* __restrict__ tkw,
    _Float16* __restrict__ slots) {
  int e = blockIdx.x & 7;              // consecutive blocks -> different XCDs
  int m0 = (blockIdx.x >> 3) * 128;
  int count = cnt[e * 64];
  if (m0 >= count) return;
  __shared__ _Float16 Wb1[64 * 128];   // 16 KB W1 chunk [ff64][k=d 128], swizzled
  __shared__ _Float16 Wb2[128 * 64];   // 16 KB W2 chunk [d128][k=ff 64], swizzled
  __shared__ _Float16 h_s[128 * 64];   // 16 KB [tok128][ff64], swizzled
  __shared__ int alist[128];
  __shared__ float aw[128];
  int tid = threadIdx.x, lane = tid & 63, w = tid >> 6;
  int wr = w >> 2, wc = w & 3;         // 2 x 4 wave grid
  int fr = lane & 15, g = lane >> 4;

  if (tid < 128) {
    int idx = m0 + tid;
    int a = (idx < count) ? lists[(size_t)e * NT + idx] : -1;
    alist[tid] = a;
    aw[tid] = (a >= 0) ? tkw[a] : 0.f;
  }
  __syncthreads();

  // stage W1 chunk ch: rows ff_local 0..63 x 128 halves (16 granules/row).
  // source granule pre-swizzled: sg = gg ^ (((r>>2)&3)<<1)  (involution w/ read XOR)
  auto issue_w1 = [&](int ch) {
    #pragma unroll
    for (int j = 0; j < 2; j++) {
      int n = j * 512 + tid;           // 0..1023
      int r = n >> 4, gg = n & 15;
      int sg = gg ^ (((r >> 2) & 3) << 1);
      const _Float16* src = W1t + (size_t)e * (NFF * HD) + (size_t)(ch * 64 + r) * HD + sg * 8;
      gload_lds16(src, (_Float16*)Wb1 + n * 8);
    }
  };
  // stage W2 chunk ch: rows d 0..127 x 64 halves (8 granules/row)
  auto issue_w2 = [&](int ch) {
    #pragma unroll
    for (int j = 0; j < 2; j++) {
      int n = j * 512 + tid;           // 0..1023
      int r = n >> 3, gg = n & 7;
      int sg = gg ^ (((r >> 2) & 3) << 1);
      const _Float16* src = W2t + (size_t)e * (HD * NFF) + (size_t)r * NFF + ch * 64 + sg * 8;
      gload_lds16(src, (_Float16*)Wb2 + n * 8);
    }
  };

  issue_w1(0);
  // gather this wave's token rows into registers (held across all phases)
  f16x8 af[4][4];
  #pragma unroll
  for (int mi = 0; mi < 4; mi++) {
    int rloc = wr * 64 + mi * 16 + fr;
    int a = alist[rloc];
    const _Float16* tb = t_h + (size_t)(a >> 1) * HD;
    #pragma unroll
    for (int ks = 0; ks < 4; ks++) {
      f16x8 v = {0, 0, 0, 0, 0, 0, 0, 0};
      if (a >= 0) v = *(const f16x8*)(tb + ks * 32 + g * 8);
      af[mi][ks] = v;
    }
  }
  float b2v[2];
  #pragma unroll
  for (int ni = 0; ni < 2; ni++)
    b2v[ni] = b2[e * HD + wc * 32 + ni * 16 + fr];

  __syncthreads();                     // drains vmcnt: W1 chunk 0 ready

  f32x4 acc2[4][2];
  #pragma unroll
  for (int i = 0; i < 4; i++)
    #pragma unroll
    for (int j = 0; j < 2; j++) acc2[i][j] = (f32x4){0.f, 0.f, 0.f, 0.f};

  for (int ch = 0; ch < 8; ch++) {
    // ---- phase A: h(:, ch*64..) = relu(t @ W1chunk + b1) ----
    issue_w2(ch);
    float b1v = b1[e * NFF + ch * 64 + wc * 16 + fr];
    f32x4 acc1[4];
    #pragma unroll
    for (int i = 0; i < 4; i++) acc1[i] = (f32x4){0.f, 0.f, 0.f, 0.f};
    #pragma unroll
    for (int ks = 0; ks < 4; ks++) {
      int rw = wc * 16 + fr;           // ff row of chunk
      int byte = rw * 256 + ((ks * 64 + g * 16) ^ (((rw >> 2) & 3) << 5));
      f16x8 bq = *(const f16x8*)((const char*)Wb1 + byte);
      #pragma unroll
      for (int mi = 0; mi < 4; mi++)
        acc1[mi] = __builtin_amdgcn_mfma_f32_16x16x32_f16(af[mi][ks], bq, acc1[mi], 0, 0, 0);
    }
    #pragma unroll
    for (int mi = 0; mi < 4; mi++)
      #pragma unroll
      for (int r = 0; r < 4; r++) {
        int hr = wr * 64 + mi * 16 + g * 4 + r;
        int hc = wc * 16 + fr;
        int byte = hr * 128 + ((hc * 2) ^ (((hr >> 2) & 3) << 5));
        *(_Float16*)((char*)h_s + byte) = (_Float16)fmaxf(acc1[mi][r] + b1v, 0.f);
      }
    __syncthreads();                   // h ready; W2 chunk ready (vmcnt drained)
    // ---- phase B: acc2 += h(:, ch) @ W2chunk ----
    if (ch < 7) issue_w1(ch + 1);
    #pragma unroll
    for (int ks = 0; ks < 2; ks++) {
      f16x8 ah[4], bq[2];
      #pragma unroll
      for (int mi = 0; mi < 4; mi++) {
        int row = wr * 64 + mi * 16 + fr;
        int byte = row * 128 + ((ks * 64 + g * 16) ^ (((row >> 2) & 3) << 5));
        ah[mi] = *(const f16x8*)((const char*)h_s + byte);
      }
      #pragma unroll
      for (int ni = 0; ni < 2; ni++) {
        int rw = wc * 32 + ni * 16 + fr;   // d row
        int byte = rw * 128 + ((ks * 64 + g * 16) ^ (((rw >> 2) & 3) << 5));
        bq[ni] = *(const f16x8*)((const char*)Wb2 + byte);
      }
      #pragma unroll
      for (int mi = 0; mi < 4; mi++)
        #pragma unroll
        for (int ni = 0; ni < 2; ni++)
          acc2[mi][ni] = __builtin_amdgcn_mfma_f32_16x16x32_f16(ah[mi], bq[ni], acc2[mi][ni], 0, 0, 0);
    }
    __syncthreads();                   // next W1 ready; h_s safe to overwrite
  }
  // epilogue: gate-scale + fp16 scatter to slots
  #pragma unroll
  for (int mi = 0; mi < 4; mi++)
    #pragma unroll
    for (int ni = 0; ni < 2; ni++) {
      int ncol = wc * 32 + ni * 16 + fr;
      #pragma unroll
      for (int r = 0; r < 4; r++) {
        int m = wr * 64 + mi * 16 + g * 4 + r;
        int a = alist[m];
        if (a >= 0)
          slots[(size_t)a * HD + ncol] = (_Float16)(aw[m] * (acc2[mi][ni][r] + b2v[ni]));
      }
    }
}

// combine slots -> momentum update -> residual -> LayerNorm; writes nm_out (fp32) + out_h (fp16)
// 1 wave per token (2 elems/lane), 4 tokens/block
__global__ __launch_bounds__(256) void combine_ln_kernel(
    const _Float16* __restrict__ slots, const float* __restrict__ momentum,
    const _Float16* __restrict__ t_h, const float* __restrict__ ln_g, const float* __restrict__ ln_b,
    float* __restrict__ nm_out, _Float16* __restrict__ out_h) {
  int w = threadIdx.x >> 6, lane = threadIdx.x & 63;
  int tok = blockIdx.x * 4 + w;
  int d0 = lane * 2;
  f16x2 s0 = *(const f16x2*)(slots + (size_t)tok * 256 + d0);
  f16x2 s1 = *(const f16x2*)(slots + (size_t)tok * 256 + 128 + d0);
  float2 mo = *(const float2*)(momentum + (size_t)tok * HD + d0);
  f16x2 tv = *(const f16x2*)(t_h + (size_t)tok * HD + d0);
  float nm0 = -((float)s0.x + (float)s1.x) + MU_F * mo.x;
  float nm1 = -((float)s0.y + (float)s1.y) + MU_F * mo.y;
  float2 nm2; nm2.x = nm0; nm2.y = nm1;
  *(float2*)(nm_out + (size_t)tok * HD + d0) = nm2;
  float r0 = (float)tv.x + nm0;
  float r1 = (float)tv.y + nm1;
  float s = r0 + r1, sq = r0 * r0 + r1 * r1;
  #pragma unroll
  for (int m = 1; m < 64; m <<= 1) { s += __shfl_xor(s, m, 64); sq += __shfl_xor(sq, m, 64); }
  float mean = s * (1.f / 128.f);
  float var = sq * (1.f / 128.f) - mean * mean;
  float is = rsqrtf(var + LN_EPS_F);
  float y0 = (r0 - mean) * is * ln_g[d0] + ln_b[d0];
  float y1 = (r1 - mean) * is * ln_g[d0 + 1] + ln_b[d0 + 1];
  f16x2 yo = { (_Float16)y0, (_Float16)y1 };
  *(f16x2*)(out_h + (size_t)tok * HD + d0) = yo;
}

extern "C" void kernel_launch(void* const* d_in, const int* in_sizes, int n_in,
                              void* d_out, int out_size, void* d_ws, size_t ws_size,
                              hipStream_t stream) {
  const float* x        = (const float*)d_in[0];
  const float* momentum = (const float*)d_in[1];
  const float* split_W  = (const float*)d_in[2];
  const float* split_b  = (const float*)d_in[3];
  const float* gate_W   = (const float*)d_in[4];
  const float* gate_b   = (const float*)d_in[5];
  const float* W1       = (const float*)d_in[6];
  const float* b1       = (const float*)d_in[7];
  const float* W2       = (const float*)d_in[8];
  const float* b2       = (const float*)d_in[9];
  const float* ln_g     = (const float*)d_in[10];
  const float* ln_b     = (const float*)d_in[11];
  const float* merge_W  = (const float*)d_in[12];
  const float* merge_b  = (const float*)d_in[13];
  float* final_out = (float*)d_out;
  float* nm_out    = final_out + (size_t)NBS * ND;

  char* ws = (char*)d_ws;
  size_t off = 0;
  auto alloc = [&](size_t bytes) { void* p = ws + off; off = (off + bytes + 255) & ~(size_t)255; return p; };
  _Float16* x_h   = (_Float16*)alloc((size_t)NBS * ND * 2);
  _Float16* t_h   = (_Float16*)alloc((size_t)NT * HD * 2);
  _Float16* out_h = (_Float16*)alloc((size_t)NT * HD * 2);
  _Float16* sWt   = (_Float16*)alloc((size_t)ND * ND * 2);
  _Float16* mWt   = (_Float16*)alloc((size_t)ND * ND * 2);
  _Float16* W1t   = (_Float16*)alloc((size_t)NE * HD * NFF * 2);
  _Float16* W2t   = (_Float16*)alloc((size_t)NE * HD * NFF * 2);
  double*   G     = (double*)alloc((size_t)ND * 64 * 8);
  double*   gbias = (double*)alloc(64 * 8);
  float*    tkw   = (float*)alloc((size_t)NT * 2 * 4);
  int*      lists = (int*)alloc((size_t)NE * NT * 4);
  int*      cnt   = (int*)alloc(512 * 4);
  _Float16* slots = (_Float16*)alloc((size_t)NT * 2 * HD * 2);
  (void)in_sizes; (void)n_in; (void)out_size; (void)ws_size;

  zero_cnt_kernel<<<1, 512, 0, stream>>>(cnt);
  cvt_f16_kernel<<<(NBS * ND / 4 + 255) / 256, 256, 0, stream>>>(x, x_h, NBS * ND / 4);
  tr_cvt_kernel<<<dim3(32, 32, 1), dim3(32, 8), 0, stream>>>(split_W, sWt, ND, ND);
  tr_cvt_kernel<<<dim3(32, 32, 1), dim3(32, 8), 0, stream>>>(merge_W, mWt, ND, ND);
  tr_cvt_kernel<<<dim3(16, 4, 8), dim3(32, 8), 0, stream>>>(W1, W1t, HD, NFF);
  tr_cvt_kernel<<<dim3(4, 16, 8), dim3(32, 8), 0, stream>>>(W2, W2t, NFF, HD);
  build_G_kernel<<<256, 256, 0, stream>>>(split_W, split_b, gate_W, gate_b, G, gbias);
  // t = x @ split_W + split_b   (fp16 out for downstream MFMA)
  gemm_f16_kernel<<<dim3(8, 64), 256, 0, stream>>>(x_h, sWt, split_b, nullptr, t_h, NBS, ND, ND);
  gate_kernel<<<512, 256, 0, stream>>>(x, G, gbias, tkw, lists, cnt);
  expert_kernel<<<NE * 512, 512, 0, stream>>>(t_h, W1t, W2t, b1, b2, cnt, lists, tkw, slots);
  combine_ln_kernel<<<NT / 4, 256, 0, stream>>>(slots, momentum, t_h, ln_g, ln_b, nm_out, out_h);
  // final = out @ merge_W + merge_b
  gemm_f16_kernel<<<dim3(8, 64), 256, 0, stream>>>(out_h, mWt, merge_b, final_out, nullptr, NBS, ND, ND);
}

// Round 8
// 256.147 us; speedup vs baseline: 1.4886x; 1.4886x over previous
//
#include <hip/hip_runtime.h>

#define NBATCH 4
#define NS 2048
#define ND 1024
#define NH 8
#define HD 128
#define NFF 512
#define NE 8
#define NT 65536       /* B*S*H tokens */
#define NBS 8192       /* B*S rows */
#define MU_F 0.7f
#define LN_EPS_F 1e-5f

typedef __attribute__((ext_vector_type(4))) float f32x4;
typedef __attribute__((ext_vector_type(2))) double f64x2;
typedef __attribute__((ext_vector_type(8))) _Float16 f16x8;
typedef __attribute__((ext_vector_type(4))) _Float16 f16x4;
typedef __attribute__((ext_vector_type(2))) _Float16 f16x2;

__device__ __forceinline__ void gload_lds16(const void* g, void* l) {
  __builtin_amdgcn_global_load_lds(
      (const __attribute__((address_space(1))) unsigned int*)g,
      (__attribute__((address_space(3))) unsigned int*)l, 16, 0, 0);
}

// cnt is strided: cnt[e*64] so the 8 counters live in different cache lines/TCC channels
__global__ void zero_cnt_kernel(int* cnt) {
  cnt[threadIdx.x] = 0;
}

// plain fp32 -> fp16 convert, 4 elems/thread
__global__ void cvt_f16_kernel(const float* __restrict__ in, _Float16* __restrict__ out, int n4) {
  int i = blockIdx.x * blockDim.x + threadIdx.x;
  if (i >= n4) return;
  float4 v = ((const float4*)in)[i];
  f16x4 h = { (_Float16)v.x, (_Float16)v.y, (_Float16)v.z, (_Float16)v.w };
  *(f16x4*)(out + (size_t)i * 4) = h;
}

// batched transpose + convert: in [batch][R][C] f32 -> out [batch][C][R] f16
// R, C multiples of 32. block (32,8), grid (C/32, R/32, batch)
__global__ void tr_cvt_kernel(const float* __restrict__ in, _Float16* __restrict__ out, int R, int C) {
  __shared__ float tile[32][33];
  int b = blockIdx.z;
  const float* inp = in + (size_t)b * R * C;
  _Float16* outp = out + (size_t)b * R * C;
  int c = blockIdx.x * 32 + threadIdx.x;
  int r0 = blockIdx.y * 32;
  #pragma unroll
  for (int i = 0; i < 4; i++) {
    int r = r0 + threadIdx.y + i * 8;
    tile[threadIdx.y + i * 8][threadIdx.x] = inp[(size_t)r * C + c];
  }
  __syncthreads();
  int rr = r0 + threadIdx.x;
  #pragma unroll
  for (int i = 0; i < 4; i++) {
    int cc = blockIdx.x * 32 + threadIdx.y + i * 8;
    outp[(size_t)cc * R + rr] = (_Float16)tile[threadIdx.x][threadIdx.y + i * 8];
  }
}

// G[d][o] (o = h*8+e) = sum_j split_W[d][h*128+j] * gate_W[j][e]  (fp64)
// gbias[o] = split_b[h*128:] . gate_W[:,e] + gate_b[e]
__global__ void build_G_kernel(const float* __restrict__ split_W, const float* __restrict__ split_b,
                               const float* __restrict__ gate_W, const float* __restrict__ gate_b,
                               double* __restrict__ G, double* __restrict__ gbias) {
  int idx = blockIdx.x * 256 + threadIdx.x;   // 65536 total
  int d = idx >> 6, o = idx & 63, h = o >> 3, e = o & 7;
  double acc = 0.0;
  for (int j = 0; j < 128; j++)
    acc += (double)split_W[(size_t)d * ND + h * 128 + j] * (double)gate_W[j * 8 + e];
  G[idx] = acc;
  if (idx < 64) {
    double bacc = 0.0;
    for (int j = 0; j < 128; j++)
      bacc += (double)split_b[h * 128 + j] * (double)gate_W[j * 8 + e];
    gbias[idx] = bacc + (double)gate_b[e];
  }
}

// fp64 logits = x @ G + gbias, top-2 per (row,h), softmax, per-expert lists.
// v4: LDS fp64 mini-GEMM (conflict-free Gsx[kp][col] f64x2 layout) +
// hierarchical atomics (LDS counts -> 8 strided global atomics/block).
__global__ __launch_bounds__(256) void gate_kernel(const float* __restrict__ x,
    const double* __restrict__ G, const double* __restrict__ gbias,
    float* __restrict__ tkw, int* __restrict__ lists, int* __restrict__ cnt) {
  __shared__ f64x2 Gsx[32 * 64];     // 32 KB, [kp][col]
  __shared__ double xsd[16][66];     // 8.25 KB
  __shared__ double lg[16 * 64];     // 8 KB
  __shared__ int lcnt[8];
  __shared__ int lbase[8];
  int tid = threadIdx.x, lane = tid & 63, w = tid >> 6;
  int bs0 = blockIdx.x * 16;
  double acc[4];
  #pragma unroll
  for (int r = 0; r < 4; r++) acc[r] = 0.0;
  int xrow = tid >> 4, xc4 = tid & 15;
  const double* xr = &xsd[0][0] + (w * 4) * 66;
  if (tid < 8) lcnt[tid] = 0;

  for (int ch = 0; ch < 16; ch++) {
    __syncthreads();           // previous chunk's reads complete before overwrite
    float4 xv4 = *(const float4*)(x + (size_t)(bs0 + xrow) * ND + ch * 64 + xc4 * 4);
    f64x2 xa = { (double)xv4.x, (double)xv4.y };
    f64x2 xb = { (double)xv4.z, (double)xv4.w };
    *(f64x2*)&xsd[xrow][xc4 * 4]     = xa;
    *(f64x2*)&xsd[xrow][xc4 * 4 + 2] = xb;
    #pragma unroll
    for (int i = 0; i < 8; i++) {
      int idx = i * 256 + tid, kp = idx >> 6, c = idx & 63;
      const double* gp = G + (size_t)(ch * 64 + kp * 2) * 64 + c;
      f64x2 gv = { gp[0], gp[64] };
      Gsx[idx] = gv;
    }
    __syncthreads();
    #pragma unroll 4
    for (int kp = 0; kp < 32; kp++) {
      f64x2 g = Gsx[kp * 64 + lane];       // contiguous 16B/lane: conflict-free
      #pragma unroll
      for (int r = 0; r < 4; r++) {
        f64x2 xv = *(const f64x2*)(xr + r * 66 + kp * 2);   // broadcast
        acc[r] += xv.x * g.x;
        acc[r] += xv.y * g.y;
      }
    }
  }
  double gb = gbias[lane];
  #pragma unroll
  for (int r = 0; r < 4; r++)
    lg[(w * 4 + r) * 64 + lane] = acc[r] + gb;
  __syncthreads();

  int i1 = 0, i2 = 0, token = 0, p1 = 0, p2 = 0;
  if (tid < 128) {
    int row = tid >> 3, h = tid & 7;
    const double* L = lg + row * 64 + h * 8;
    double v1 = L[0];
    #pragma unroll
    for (int e2 = 1; e2 < 8; e2++) if (L[e2] > v1) { v1 = L[e2]; i1 = e2; }
    i2 = -1; double v2 = -1e300;
    #pragma unroll
    for (int e2 = 0; e2 < 8; e2++) if (e2 != i1 && L[e2] > v2) { v2 = L[e2]; i2 = e2; }
    float ex = expf((float)(v2 - v1));        // <= 1
    float den = 1.f + ex;
    float g1 = 1.f / den, g2 = ex / den;
    token = (bs0 + row) * 8 + h;
    tkw[token * 2]     = g1;
    tkw[token * 2 + 1] = g2;
    p1 = atomicAdd(&lcnt[i1], 1);             // LDS atomics: cheap
    p2 = atomicAdd(&lcnt[i2], 1);
  }
  __syncthreads();
  if (tid < 8) lbase[tid] = atomicAdd(cnt + tid * 64, lcnt[tid]);   // 8 global atomics/block
  __syncthreads();
  if (tid < 128) {
    lists[(size_t)i1 * NT + lbase[i1] + p1] = token * 2;
    lists[(size_t)i2 * NT + lbase[i2] + p2] = token * 2 + 1;
  }
}

// C[M][N] = A[M][K] @ Bt[N][K]^T + bias; fp16 inputs, fp32 acc.
// 128x128 tile, BK=32, 4 waves (2x2 of 64x64), global_load_lds width 16.
__global__ __launch_bounds__(256) void gemm_f16_kernel(
    const _Float16* __restrict__ A, const _Float16* __restrict__ Bt,
    const float* __restrict__ bias, float* __restrict__ Cf, _Float16* __restrict__ Ch,
    int M, int N, int Kd) {
  __shared__ _Float16 As[128 * 32];
  __shared__ _Float16 Bs[128 * 32];
  int tid = threadIdx.x, lane = tid & 63, w = tid >> 6;
  int wr = w >> 1, wc = w & 1;
  int m0 = blockIdx.y * 128, n0 = blockIdx.x * 128;
  f32x4 acc[4][4];
  #pragma unroll
  for (int i = 0; i < 4; i++)
    #pragma unroll
    for (int j = 0; j < 4; j++) acc[i][j] = (f32x4){0.f, 0.f, 0.f, 0.f};
  int srow = lane >> 2, scol = (lane & 3) * 8;
  int fr = lane & 15, ko = (lane >> 4) * 8;
  const _Float16* Ag = A + (size_t)(m0 + srow) * Kd + scol;
  const _Float16* Bg = Bt + (size_t)(n0 + srow) * Kd + scol;

  for (int k0 = 0; k0 < Kd; k0 += 32) {
    #pragma unroll
    for (int j = 0; j < 2; j++) {
      int rb = (w * 2 + j) * 16;
      gload_lds16(Ag + (size_t)rb * Kd + k0, As + rb * 32);
      gload_lds16(Bg + (size_t)rb * Kd + k0, Bs + rb * 32);
    }
    __syncthreads();
    f16x8 af[4], bq[4];
    #pragma unroll
    for (int mi = 0; mi < 4; mi++) af[mi] = *(const f16x8*)(As + (wr * 64 + mi * 16 + fr) * 32 + ko);
    #pragma unroll
    for (int ni = 0; ni < 4; ni++) bq[ni] = *(const f16x8*)(Bs + (wc * 64 + ni * 16 + fr) * 32 + ko);
    __syncthreads();
    #pragma unroll
    for (int mi = 0; mi < 4; mi++)
      #pragma unroll
      for (int ni = 0; ni < 4; ni++)
        acc[mi][ni] = __builtin_amdgcn_mfma_f32_16x16x32_f16(af[mi], bq[ni], acc[mi][ni], 0, 0, 0);
  }
  int rbase = m0 + wr * 64 + ((lane >> 4) << 2);
  int cbase = n0 + wc * 64 + (lane & 15);
  #pragma unroll
  for (int mi = 0; mi < 4; mi++)
    #pragma unroll
    for (int ni = 0; ni < 4; ni++) {
      int cc = cbase + ni * 16;
      float bv = bias ? bias[cc] : 0.f;
      #pragma unroll
      for (int r = 0; r < 4; r++) {
        int rr = rbase + mi * 16 + r;
        float v = acc[mi][ni][r] + bv;
        if (Cf) Cf[(size_t)rr * N + cc] = v;
        if (Ch) Ch[(size_t)rr * N + cc] = (_Float16)v;
      }
    }
}

// Grouped expert kernel v5: 64-ff chunk pipeline, wave grid 4x2 (tile 32x64 ->
// ~110 VGPR, no spill), __launch_bounds__(512,2) caps VGPR at 128 (empirical:
// cap = 256/arg2; (512,4) capped at 64 -> catastrophic spill in v4b).
// LDS 49KB + VGPR<=128 -> 2 blocks/CU. Uniform swizzle key (row&7)<<4 on Wb1/
// Wb2/h_s: all b128 reads and h-writes are <=2-way (free, m136). Stage sources
// pre-swizzled with the same involution sg = gg^(r&7) (rule #21).
__global__ __launch_bounds__(512, 2) void expert_kernel(
    const _Float16* __restrict__ t_h, const _Float16* __restrict__ W1t, const _Float16* __restrict__ W2t,
    const float* __restrict__ b1, const float* __restrict__ b2,
    const int* __restrict__ cnt, const int* __restrict__ lists, const float* __restrict__ tkw,
    _Float16* __restrict__ slots) {
  int e = blockIdx.x & 7;              // consecutive blocks -> different XCDs
  int m0 = (blockIdx.x >> 3) * 128;
  int count = cnt[e * 64];
  if (m0 >= count) return;
  __shared__ _Float16 Wb1[64 * 128];   // 16 KB W1 chunk [ff64][d128] 256B rows
  __shared__ _Float16 Wb2[128 * 64];   // 16 KB W2 chunk [d128][ff64] 128B rows
  __shared__ _Float16 h_s[128 * 64];   // 16 KB [tok128][ff64] 128B rows
  __shared__ int alist[128];
  __shared__ float aw[128];
  int tid = threadIdx.x, lane = tid & 63, w = tid >> 6;
  int wr = w >> 1, wc = w & 1;         // 4 row-quarters (32) x 2 col-halves (64)
  int fr = lane & 15, g = lane >> 4;

  if (tid < 128) {
    int idx = m0 + tid;
    int a = (idx < count) ? lists[(size_t)e * NT + idx] : -1;
    alist[tid] = a;
    aw[tid] = (a >= 0) ? tkw[a] : 0.f;
  }
  __syncthreads();

  auto issue_w1 = [&](int ch) {
    #pragma unroll
    for (int j = 0; j < 2; j++) {
      int n = j * 512 + tid;           // 0..1023 granules (16 per 256B row)
      int r = n >> 4, gg = n & 15;
      int sg = gg ^ (r & 7);
      const _Float16* src = W1t + (size_t)e * (NFF * HD) + (size_t)(ch * 64 + r) * HD + sg * 8;
      gload_lds16(src, (_Float16*)Wb1 + n * 8);
    }
  };
  auto issue_w2 = [&](int ch) {
    #pragma unroll
    for (int j = 0; j < 2; j++) {
      int n = j * 512 + tid;           // 0..1023 granules (8 per 128B row)
      int r = n >> 3, gg = n & 7;
      int sg = gg ^ (r & 7);
      const _Float16* src = W2t + (size_t)e * (HD * NFF) + (size_t)r * NFF + ch * 64 + sg * 8;
      gload_lds16(src, (_Float16*)Wb2 + n * 8);
    }
  };

  issue_w1(0);
  // gather this wave's 32 token rows into registers (held across all phases)
  f16x8 af[2][4];
  #pragma unroll
  for (int mi = 0; mi < 2; mi++) {
    int rloc = wr * 32 + mi * 16 + fr;
    int a = alist[rloc];
    const _Float16* tb = t_h + (size_t)(a >> 1) * HD;
    #pragma unroll
    for (int ks = 0; ks < 4; ks++) {
      f16x8 v = {0, 0, 0, 0, 0, 0, 0, 0};
      if (a >= 0) v = *(const f16x8*)(tb + ks * 32 + g * 8);
      af[mi][ks] = v;
    }
  }
  float b2v[4];
  #pragma unroll
  for (int ni = 0; ni < 4; ni++)
    b2v[ni] = b2[e * HD + wc * 64 + ni * 16 + fr];

  __syncthreads();                     // drains vmcnt: W1 chunk 0 ready

  f32x4 acc2[2][4];
  #pragma unroll
  for (int i = 0; i < 2; i++)
    #pragma unroll
    for (int j = 0; j < 4; j++) acc2[i][j] = (f32x4){0.f, 0.f, 0.f, 0.f};

  for (int ch = 0; ch < 8; ch++) {
    // ---- phase A: h(:, ch*64..) = relu(t @ W1chunk + b1) ----
    issue_w2(ch);
    float b1v[2];
    #pragma unroll
    for (int ni = 0; ni < 2; ni++)
      b1v[ni] = b1[e * NFF + ch * 64 + wc * 32 + ni * 16 + fr];
    f32x4 acc1[2][2];
    #pragma unroll
    for (int i = 0; i < 2; i++)
      #pragma unroll
      for (int j = 0; j < 2; j++) acc1[i][j] = (f32x4){0.f, 0.f, 0.f, 0.f};
    #pragma unroll
    for (int ks = 0; ks < 4; ks++) {
      f16x8 bq[2];
      #pragma unroll
      for (int ni = 0; ni < 2; ni++) {
        int rw = wc * 32 + ni * 16 + fr;       // ff row of chunk (0..63)
        int byte = rw * 256 + ((ks * 64 + g * 16) ^ ((rw & 7) << 4));
        bq[ni] = *(const f16x8*)((const char*)Wb1 + byte);
      }
      #pragma unroll
      for (int mi = 0; mi < 2; mi++)
        #pragma unroll
        for (int ni = 0; ni < 2; ni++)
          acc1[mi][ni] = __builtin_amdgcn_mfma_f32_16x16x32_f16(af[mi][ks], bq[ni], acc1[mi][ni], 0, 0, 0);
    }
    #pragma unroll
    for (int mi = 0; mi < 2; mi++)
      #pragma unroll
      for (int ni = 0; ni < 2; ni++) {
        int hc = wc * 32 + ni * 16 + fr;
        #pragma unroll
        for (int r = 0; r < 4; r++) {
          int hr = wr * 32 + mi * 16 + g * 4 + r;
          int byte = hr * 128 + ((hc * 2) ^ ((hr & 7) << 4));
          *(_Float16*)((char*)h_s + byte) = (_Float16)fmaxf(acc1[mi][ni][r] + b1v[ni], 0.f);
        }
      }
    __syncthreads();                   // h ready; W2 chunk ready (vmcnt drained)
    // ---- phase B: acc2 += h(:, ch) @ W2chunk ----
    if (ch < 7) issue_w1(ch + 1);
    #pragma unroll
    for (int ks = 0; ks < 2; ks++) {
      f16x8 ah[2], bq[4];
      #pragma unroll
      for (int mi = 0; mi < 2; mi++) {
        int row = wr * 32 + mi * 16 + fr;
        int byte = row * 128 + ((ks * 64 + g * 16) ^ ((row & 7) << 4));
        ah[mi] = *(const f16x8*)((const char*)h_s + byte);
      }
      #pragma unroll
      for (int ni = 0; ni < 4; ni++) {
        int rw = wc * 64 + ni * 16 + fr;       // d row (0..127)
        int byte = rw * 128 + ((ks * 64 + g * 16) ^ ((rw & 7) << 4));
        bq[ni] = *(const f16x8*)((const char*)Wb2 + byte);
      }
      #pragma unroll
      for (int mi = 0; mi < 2; mi++)
        #pragma unroll
        for (int ni = 0; ni < 4; ni++)
          acc2[mi][ni] = __builtin_amdgcn_mfma_f32_16x16x32_f16(ah[mi], bq[ni], acc2[mi][ni], 0, 0, 0);
    }
    __syncthreads();                   // next W1 ready; h_s safe to overwrite
  }
  // epilogue: gate-scale + fp16 scatter to slots
  #pragma unroll
  for (int mi = 0; mi < 2; mi++)
    #pragma unroll
    for (int ni = 0; ni < 4; ni++) {
      int ncol = wc * 64 + ni * 16 + fr;
      #pragma unroll
      for (int r = 0; r < 4; r++) {
        int m = wr * 32 + mi * 16 + g * 4 + r;
        int a = alist[m];
        if (a >= 0)
          slots[(size_t)a * HD + ncol] = (_Float16)(aw[m] * (acc2[mi][ni][r] + b2v[ni]));
      }
    }
}

// combine slots -> momentum update -> residual -> LayerNorm; writes nm_out (fp32) + out_h (fp16)
// 1 wave per token (2 elems/lane), 4 tokens/block
__global__ __launch_bounds__(256) void combine_ln_kernel(
    const _Float16* __restrict__ slots, const float* __restrict__ momentum,
    const _Float16* __restrict__ t_h, const float* __restrict__ ln_g, const float* __restrict__ ln_b,
    float* __restrict__ nm_out, _Float16* __restrict__ out_h) {
  int w = threadIdx.x >> 6, lane = threadIdx.x & 63;
  int tok = blockIdx.x * 4 + w;
  int d0 = lane * 2;
  f16x2 s0 = *(const f16x2*)(slots + (size_t)tok * 256 + d0);
  f16x2 s1 = *(const f16x2*)(slots + (size_t)tok * 256 + 128 + d0);
  float2 mo = *(const float2*)(momentum + (size_t)tok * HD + d0);
  f16x2 tv = *(const f16x2*)(t_h + (size_t)tok * HD + d0);
  float nm0 = -((float)s0.x + (float)s1.x) + MU_F * mo.x;
  float nm1 = -((float)s0.y + (float)s1.y) + MU_F * mo.y;
  float2 nm2; nm2.x = nm0; nm2.y = nm1;
  *(float2*)(nm_out + (size_t)tok * HD + d0) = nm2;
  float r0 = (float)tv.x + nm0;
  float r1 = (float)tv.y + nm1;
  float s = r0 + r1, sq = r0 * r0 + r1 * r1;
  #pragma unroll
  for (int m = 1; m < 64; m <<= 1) { s += __shfl_xor(s, m, 64); sq += __shfl_xor(sq, m, 64); }
  float mean = s * (1.f / 128.f);
  float var = sq * (1.f / 128.f) - mean * mean;
  float is = rsqrtf(var + LN_EPS_F);
  float y0 = (r0 - mean) * is * ln_g[d0] + ln_b[d0];
  float y1 = (r1 - mean) * is * ln_g[d0 + 1] + ln_b[d0 + 1];
  f16x2 yo = { (_Float16)y0, (_Float16)y1 };
  *(f16x2*)(out_h + (size_t)tok * HD + d0) = yo;
}

extern "C" void kernel_launch(void* const* d_in, const int* in_sizes, int n_in,
                              void* d_out, int out_size, void* d_ws, size_t ws_size,
                              hipStream_t stream) {
  const float* x        = (const float*)d_in[0];
  const float* momentum = (const float*)d_in[1];
  const float* split_W  = (const float*)d_in[2];
  const float* split_b  = (const float*)d_in[3];
  const float* gate_W   = (const float*)d_in[4];
  const float* gate_b   = (const float*)d_in[5];
  const float* W1       = (const float*)d_in[6];
  const float* b1       = (const float*)d_in[7];
  const float* W2       = (const float*)d_in[8];
  const float* b2       = (const float*)d_in[9];
  const float* ln_g     = (const float*)d_in[10];
  const float* ln_b     = (const float*)d_in[11];
  const float* merge_W  = (const float*)d_in[12];
  const float* merge_b  = (const float*)d_in[13];
  float* final_out = (float*)d_out;
  float* nm_out    = final_out + (size_t)NBS * ND;

  char* ws = (char*)d_ws;
  size_t off = 0;
  auto alloc = [&](size_t bytes) { void* p = ws + off; off = (off + bytes + 255) & ~(size_t)255; return p; };
  _Float16* x_h   = (_Float16*)alloc((size_t)NBS * ND * 2);
  _Float16* t_h   = (_Float16*)alloc((size_t)NT * HD * 2);
  _Float16* out_h = (_Float16*)alloc((size_t)NT * HD * 2);
  _Float16* sWt   = (_Float16*)alloc((size_t)ND * ND * 2);
  _Float16* mWt   = (_Float16*)alloc((size_t)ND * ND * 2);
  _Float16* W1t   = (_Float16*)alloc((size_t)NE * HD * NFF * 2);
  _Float16* W2t   = (_Float16*)alloc((size_t)NE * HD * NFF * 2);
  double*   G     = (double*)alloc((size_t)ND * 64 * 8);
  double*   gbias = (double*)alloc(64 * 8);
  float*    tkw   = (float*)alloc((size_t)NT * 2 * 4);
  int*      lists = (int*)alloc((size_t)NE * NT * 4);
  int*      cnt   = (int*)alloc(512 * 4);
  _Float16* slots = (_Float16*)alloc((size_t)NT * 2 * HD * 2);
  (void)in_sizes; (void)n_in; (void)out_size; (void)ws_size;

  zero_cnt_kernel<<<1, 512, 0, stream>>>(cnt);
  cvt_f16_kernel<<<(NBS * ND / 4 + 255) / 256, 256, 0, stream>>>(x, x_h, NBS * ND / 4);
  tr_cvt_kernel<<<dim3(32, 32, 1), dim3(32, 8), 0, stream>>>(split_W, sWt, ND, ND);
  tr_cvt_kernel<<<dim3(32, 32, 1), dim3(32, 8), 0, stream>>>(merge_W, mWt, ND, ND);
  tr_cvt_kernel<<<dim3(16, 4, 8), dim3(32, 8), 0, stream>>>(W1, W1t, HD, NFF);
  tr_cvt_kernel<<<dim3(4, 16, 8), dim3(32, 8), 0, stream>>>(W2, W2t, NFF, HD);
  build_G_kernel<<<256, 256, 0, stream>>>(split_W, split_b, gate_W, gate_b, G, gbias);
  // t = x @ split_W + split_b   (fp16 out for downstream MFMA)
  gemm_f16_kernel<<<dim3(8, 64), 256, 0, stream>>>(x_h, sWt, split_b, nullptr, t_h, NBS, ND, ND);
  gate_kernel<<<512, 256, 0, stream>>>(x, G, gbias, tkw, lists, cnt);
  expert_kernel<<<NE * 512, 512, 0, stream>>>(t_h, W1t, W2t, b1, b2, cnt, lists, tkw, slots);
  combine_ln_kernel<<<NT / 4, 256, 0, stream>>>(slots, momentum, t_h, ln_g, ln_b, nm_out, out_h);
  // final = out @ merge_W + merge_b
  gemm_f16_kernel<<<dim3(8, 64), 256, 0, stream>>>(out_h, mWt, merge_b, final_out, nullptr, NBS, ND, ND);
}

// Round 9
// 250.826 us; speedup vs baseline: 1.5202x; 1.0212x over previous
//
#include <hip/hip_runtime.h>

#define NBATCH 4
#define NS 2048
#define ND 1024
#define NH 8
#define HD 128
#define NFF 512
#define NE 8
#define NT 65536       /* B*S*H tokens */
#define NBS 8192       /* B*S rows */
#define MU_F 0.7f
#define LN_EPS_F 1e-5f

typedef __attribute__((ext_vector_type(4))) float f32x4;
typedef __attribute__((ext_vector_type(2))) double f64x2;
typedef __attribute__((ext_vector_type(8))) _Float16 f16x8;
typedef __attribute__((ext_vector_type(4))) _Float16 f16x4;
typedef __attribute__((ext_vector_type(2))) _Float16 f16x2;

__device__ __forceinline__ void gload_lds16(const void* g, void* l) {
  __builtin_amdgcn_global_load_lds(
      (const __attribute__((address_space(1))) unsigned int*)g,
      (__attribute__((address_space(3))) unsigned int*)l, 16, 0, 0);
}

// cnt is strided: cnt[e*64] so the 8 counters live in different cache lines/TCC channels
__global__ void zero_cnt_kernel(int* cnt) {
  cnt[threadIdx.x] = 0;
}

// batched transpose + convert: in [batch][R][C] f32 -> out [batch][C][R] f16
// R, C multiples of 32. block (32,8), grid (C/32, R/32, batch)
__global__ void tr_cvt_kernel(const float* __restrict__ in, _Float16* __restrict__ out, int R, int C) {
  __shared__ float tile[32][33];
  int b = blockIdx.z;
  const float* inp = in + (size_t)b * R * C;
  _Float16* outp = out + (size_t)b * R * C;
  int c = blockIdx.x * 32 + threadIdx.x;
  int r0 = blockIdx.y * 32;
  #pragma unroll
  for (int i = 0; i < 4; i++) {
    int r = r0 + threadIdx.y + i * 8;
    tile[threadIdx.y + i * 8][threadIdx.x] = inp[(size_t)r * C + c];
  }
  __syncthreads();
  int rr = r0 + threadIdx.x;
  #pragma unroll
  for (int i = 0; i < 4; i++) {
    int cc = blockIdx.x * 32 + threadIdx.y + i * 8;
    outp[(size_t)cc * R + rr] = (_Float16)tile[threadIdx.x][threadIdx.y + i * 8];
  }
}

// Gx2[kp*64 + o] = { G[2kp][o], G[2kp+1][o] } (fp64), o = h*8+e
// G[d][o] = sum_j split_W[d][h*128+j] * gate_W[j][e]
// gbias[o] = split_b[h*128:] . gate_W[:,e] + gate_b[e]
// grid 128 x 256 (32768 threads)
__global__ void build_G_kernel(const float* __restrict__ split_W, const float* __restrict__ split_b,
                               const float* __restrict__ gate_W, const float* __restrict__ gate_b,
                               f64x2* __restrict__ Gx2, double* __restrict__ gbias) {
  int idx = blockIdx.x * 256 + threadIdx.x;   // kp*64 + o, 32768 total
  int kp = idx >> 6, o = idx & 63, h = o >> 3, e = o & 7;
  int d0 = kp * 2;
  double a0 = 0.0, a1 = 0.0;
  const float* r0 = split_W + (size_t)d0 * ND + h * 128;
  const float* r1 = r0 + ND;
  for (int j = 0; j < 128; j++) {
    double w = (double)gate_W[j * 8 + e];
    a0 += (double)r0[j] * w;
    a1 += (double)r1[j] * w;
  }
  f64x2 gv = { a0, a1 };
  Gx2[idx] = gv;
  if (idx < 64) {
    double bacc = 0.0;
    for (int j = 0; j < 128; j++)
      bacc += (double)split_b[h * 128 + j] * (double)gate_W[j * 8 + e];
    gbias[idx] = bacc + (double)gate_b[e];
  }
}

// fp64 logits = x @ G + gbias, top-2 per (row,h), softmax, per-expert lists.
// v5: G read DIRECTLY from global (Gx2 [kp][col] f64x2 layout: 1KB/wave coalesced,
// L2-resident 512KB) -- no LDS round-trip for G (v4's 4x-amplified Gsx reads).
// x staged once in LDS as double (broadcast reads); ALSO emits x_h (fp16 convert
// fused -- replaces the standalone cvt kernel). Hierarchical atomics as v4.
__global__ __launch_bounds__(256) void gate_kernel(const float* __restrict__ x,
    const f64x2* __restrict__ Gx2, const double* __restrict__ gbias,
    _Float16* __restrict__ x_h,
    float* __restrict__ tkw, int* __restrict__ lists, int* __restrict__ cnt) {
  __shared__ double xsd[16][66];     // 8.25 KB
  __shared__ double lg[16 * 64];     // 8 KB
  __shared__ int lcnt[8];
  __shared__ int lbase[8];
  int tid = threadIdx.x, lane = tid & 63, w = tid >> 6;
  int bs0 = blockIdx.x * 16;
  double acc[4];
  #pragma unroll
  for (int r = 0; r < 4; r++) acc[r] = 0.0;
  int xrow = tid >> 4, xc4 = tid & 15;
  const double* xr = &xsd[0][0] + (w * 4) * 66;
  if (tid < 8) lcnt[tid] = 0;

  for (int ch = 0; ch < 16; ch++) {
    __syncthreads();           // previous chunk's reads complete before overwrite
    float4 xv4 = *(const float4*)(x + (size_t)(bs0 + xrow) * ND + ch * 64 + xc4 * 4);
    f64x2 xa = { (double)xv4.x, (double)xv4.y };
    f64x2 xb = { (double)xv4.z, (double)xv4.w };
    *(f64x2*)&xsd[xrow][xc4 * 4]     = xa;
    *(f64x2*)&xsd[xrow][xc4 * 4 + 2] = xb;
    // fused fp16 conversion of x (replaces cvt kernel)
    f16x4 xh = { (_Float16)xv4.x, (_Float16)xv4.y, (_Float16)xv4.z, (_Float16)xv4.w };
    *(f16x4*)(x_h + (size_t)(bs0 + xrow) * ND + ch * 64 + xc4 * 4) = xh;
    __syncthreads();
    const f64x2* Gc = Gx2 + (size_t)(ch * 32) * 64 + lane;
    #pragma unroll 8
    for (int kp = 0; kp < 32; kp++) {
      f64x2 g = Gc[kp * 64];               // global, coalesced 1KB/wave, L2-hit
      #pragma unroll
      for (int r = 0; r < 4; r++) {
        f64x2 xv = *(const f64x2*)(xr + r * 66 + kp * 2);   // LDS broadcast
        acc[r] += xv.x * g.x;
        acc[r] += xv.y * g.y;
      }
    }
  }
  double gb = gbias[lane];
  #pragma unroll
  for (int r = 0; r < 4; r++)
    lg[(w * 4 + r) * 64 + lane] = acc[r] + gb;
  __syncthreads();

  int i1 = 0, i2 = 0, token = 0, p1 = 0, p2 = 0;
  if (tid < 128) {
    int row = tid >> 3, h = tid & 7;
    const double* L = lg + row * 64 + h * 8;
    double v1 = L[0];
    #pragma unroll
    for (int e2 = 1; e2 < 8; e2++) if (L[e2] > v1) { v1 = L[e2]; i1 = e2; }
    i2 = -1; double v2 = -1e300;
    #pragma unroll
    for (int e2 = 0; e2 < 8; e2++) if (e2 != i1 && L[e2] > v2) { v2 = L[e2]; i2 = e2; }
    float ex = expf((float)(v2 - v1));        // <= 1
    float den = 1.f + ex;
    float g1 = 1.f / den, g2 = ex / den;
    token = (bs0 + row) * 8 + h;
    tkw[token * 2]     = g1;
    tkw[token * 2 + 1] = g2;
    p1 = atomicAdd(&lcnt[i1], 1);             // LDS atomics: cheap
    p2 = atomicAdd(&lcnt[i2], 1);
  }
  __syncthreads();
  if (tid < 8) lbase[tid] = atomicAdd(cnt + tid * 64, lcnt[tid]);   // 8 global atomics/block
  __syncthreads();
  if (tid < 128) {
    lists[(size_t)i1 * NT + lbase[i1] + p1] = token * 2;
    lists[(size_t)i2 * NT + lbase[i2] + p2] = token * 2 + 1;
  }
}

// C[M][N] = A[M][K] @ Bt[N][K]^T + bias; fp16 inputs, fp32 acc.
// 128x128 tile, BK=32, 4 waves (2x2 of 64x64), global_load_lds width 16.
__global__ __launch_bounds__(256) void gemm_f16_kernel(
    const _Float16* __restrict__ A, const _Float16* __restrict__ Bt,
    const float* __restrict__ bias, float* __restrict__ Cf, _Float16* __restrict__ Ch,
    int M, int N, int Kd) {
  __shared__ _Float16 As[128 * 32];
  __shared__ _Float16 Bs[128 * 32];
  int tid = threadIdx.x, lane = tid & 63, w = tid >> 6;
  int wr = w >> 1, wc = w & 1;
  int m0 = blockIdx.y * 128, n0 = blockIdx.x * 128;
  f32x4 acc[4][4];
  #pragma unroll
  for (int i = 0; i < 4; i++)
    #pragma unroll
    for (int j = 0; j < 4; j++) acc[i][j] = (f32x4){0.f, 0.f, 0.f, 0.f};
  int srow = lane >> 2, scol = (lane & 3) * 8;
  int fr = lane & 15, ko = (lane >> 4) * 8;
  const _Float16* Ag = A + (size_t)(m0 + srow) * Kd + scol;
  const _Float16* Bg = Bt + (size_t)(n0 + srow) * Kd + scol;

  for (int k0 = 0; k0 < Kd; k0 += 32) {
    #pragma unroll
    for (int j = 0; j < 2; j++) {
      int rb = (w * 2 + j) * 16;
      gload_lds16(Ag + (size_t)rb * Kd + k0, As + rb * 32);
      gload_lds16(Bg + (size_t)rb * Kd + k0, Bs + rb * 32);
    }
    __syncthreads();
    f16x8 af[4], bq[4];
    #pragma unroll
    for (int mi = 0; mi < 4; mi++) af[mi] = *(const f16x8*)(As + (wr * 64 + mi * 16 + fr) * 32 + ko);
    #pragma unroll
    for (int ni = 0; ni < 4; ni++) bq[ni] = *(const f16x8*)(Bs + (wc * 64 + ni * 16 + fr) * 32 + ko);
    __syncthreads();
    #pragma unroll
    for (int mi = 0; mi < 4; mi++)
      #pragma unroll
      for (int ni = 0; ni < 4; ni++)
        acc[mi][ni] = __builtin_amdgcn_mfma_f32_16x16x32_f16(af[mi], bq[ni], acc[mi][ni], 0, 0, 0);
  }
  int rbase = m0 + wr * 64 + ((lane >> 4) << 2);
  int cbase = n0 + wc * 64 + (lane & 15);
  #pragma unroll
  for (int mi = 0; mi < 4; mi++)
    #pragma unroll
    for (int ni = 0; ni < 4; ni++) {
      int cc = cbase + ni * 16;
      float bv = bias ? bias[cc] : 0.f;
      #pragma unroll
      for (int r = 0; r < 4; r++) {
        int rr = rbase + mi * 16 + r;
        float v = acc[mi][ni][r] + bv;
        if (Cf) Cf[(size_t)rr * N + cc] = v;
        if (Ch) Ch[(size_t)rr * N + cc] = (_Float16)v;
      }
    }
}

// Grouped expert kernel v6: v5 structure, swizzle key changed (row&7)->((row>>1)&7).
// Rationale (dword-level bank math): reads were already at the b128 floor, but the
// h_s scalar writes had key (g*4+r)&7 which collapses g{0,2} and g{1,3} to the same
// XOR -> 4-way write conflicts (the residual 2.1M). Key ((row>>1)&7) is distinct per
// (g, r>>1) on the write side and ((fr>>1)&7) on the read side (still floor).
// Stage sources pre-swizzled with the same involution sg = gg^((r>>1)&7) (rule #21).
__global__ __launch_bounds__(512, 2) void expert_kernel(
    const _Float16* __restrict__ t_h, const _Float16* __restrict__ W1t, const _Float16* __restrict__ W2t,
    const float* __restrict__ b1, const float* __restrict__ b2,
    const int* __restrict__ cnt, const int* __restrict__ lists, const float* __restrict__ tkw,
    _Float16* __restrict__ slots) {
  int e = blockIdx.x & 7;              // consecutive blocks -> different XCDs
  int m0 = (blockIdx.x >> 3) * 128;
  int count = cnt[e * 64];
  if (m0 >= count) return;
  __shared__ _Float16 Wb1[64 * 128];   // 16 KB W1 chunk [ff64][d128] 256B rows
  __shared__ _Float16 Wb2[128 * 64];   // 16 KB W2 chunk [d128][ff64] 128B rows
  __shared__ _Float16 h_s[128 * 64];   // 16 KB [tok128][ff64] 128B rows
  __shared__ int alist[128];
  __shared__ float aw[128];
  int tid = threadIdx.x, lane = tid & 63, w = tid >> 6;
  int wr = w >> 1, wc = w & 1;         // 4 row-quarters (32) x 2 col-halves (64)
  int fr = lane & 15, g = lane >> 4;

  if (tid < 128) {
    int idx = m0 + tid;
    int a = (idx < count) ? lists[(size_t)e * NT + idx] : -1;
    alist[tid] = a;
    aw[tid] = (a >= 0) ? tkw[a] : 0.f;
  }
  __syncthreads();

  auto issue_w1 = [&](int ch) {
    #pragma unroll
    for (int j = 0; j < 2; j++) {
      int n = j * 512 + tid;           // 0..1023 granules (16 per 256B row)
      int r = n >> 4, gg = n & 15;
      int sg = gg ^ ((r >> 1) & 7);
      const _Float16* src = W1t + (size_t)e * (NFF * HD) + (size_t)(ch * 64 + r) * HD + sg * 8;
      gload_lds16(src, (_Float16*)Wb1 + n * 8);
    }
  };
  auto issue_w2 = [&](int ch) {
    #pragma unroll
    for (int j = 0; j < 2; j++) {
      int n = j * 512 + tid;           // 0..1023 granules (8 per 128B row)
      int r = n >> 3, gg = n & 7;
      int sg = gg ^ ((r >> 1) & 7);
      const _Float16* src = W2t + (size_t)e * (HD * NFF) + (size_t)r * NFF + ch * 64 + sg * 8;
      gload_lds16(src, (_Float16*)Wb2 + n * 8);
    }
  };

  issue_w1(0);
  // gather this wave's 32 token rows into registers (held across all phases)
  f16x8 af[2][4];
  #pragma unroll
  for (int mi = 0; mi < 2; mi++) {
    int rloc = wr * 32 + mi * 16 + fr;
    int a = alist[rloc];
    const _Float16* tb = t_h + (size_t)(a >> 1) * HD;
    #pragma unroll
    for (int ks = 0; ks < 4; ks++) {
      f16x8 v = {0, 0, 0, 0, 0, 0, 0, 0};
      if (a >= 0) v = *(const f16x8*)(tb + ks * 32 + g * 8);
      af[mi][ks] = v;
    }
  }
  float b2v[4];
  #pragma unroll
  for (int ni = 0; ni < 4; ni++)
    b2v[ni] = b2[e * HD + wc * 64 + ni * 16 + fr];

  __syncthreads();                     // drains vmcnt: W1 chunk 0 ready

  f32x4 acc2[2][4];
  #pragma unroll
  for (int i = 0; i < 2; i++)
    #pragma unroll
    for (int j = 0; j < 4; j++) acc2[i][j] = (f32x4){0.f, 0.f, 0.f, 0.f};

  for (int ch = 0; ch < 8; ch++) {
    // ---- phase A: h(:, ch*64..) = relu(t @ W1chunk + b1) ----
    issue_w2(ch);
    float b1v[2];
    #pragma unroll
    for (int ni = 0; ni < 2; ni++)
      b1v[ni] = b1[e * NFF + ch * 64 + wc * 32 + ni * 16 + fr];
    f32x4 acc1[2][2];
    #pragma unroll
    for (int i = 0; i < 2; i++)
      #pragma unroll
      for (int j = 0; j < 2; j++) acc1[i][j] = (f32x4){0.f, 0.f, 0.f, 0.f};
    #pragma unroll
    for (int ks = 0; ks < 4; ks++) {
      f16x8 bq[2];
      #pragma unroll
      for (int ni = 0; ni < 2; ni++) {
        int rw = wc * 32 + ni * 16 + fr;       // ff row of chunk (0..63)
        int byte = rw * 256 + ((ks * 64 + g * 16) ^ (((rw >> 1) & 7) << 4));
        bq[ni] = *(const f16x8*)((const char*)Wb1 + byte);
      }
      #pragma unroll
      for (int mi = 0; mi < 2; mi++)
        #pragma unroll
        for (int ni = 0; ni < 2; ni++)
          acc1[mi][ni] = __builtin_amdgcn_mfma_f32_16x16x32_f16(af[mi][ks], bq[ni], acc1[mi][ni], 0, 0, 0);
    }
    #pragma unroll
    for (int mi = 0; mi < 2; mi++)
      #pragma unroll
      for (int ni = 0; ni < 2; ni++) {
        int hc = wc * 32 + ni * 16 + fr;
        #pragma unroll
        for (int r = 0; r < 4; r++) {
          int hr = wr * 32 + mi * 16 + g * 4 + r;
          int byte = hr * 128 + ((hc * 2) ^ (((hr >> 1) & 7) << 4));
          *(_Float16*)((char*)h_s + byte) = (_Float16)fmaxf(acc1[mi][ni][r] + b1v[ni], 0.f);
        }
      }
    __syncthreads();                   // h ready; W2 chunk ready (vmcnt drained)
    // ---- phase B: acc2 += h(:, ch) @ W2chunk ----
    if (ch < 7) issue_w1(ch + 1);
    #pragma unroll
    for (int ks = 0; ks < 2; ks++) {
      f16x8 ah[2], bq[4];
      #pragma unroll
      for (int mi = 0; mi < 2; mi++) {
        int row = wr * 32 + mi * 16 + fr;
        int byte = row * 128 + ((ks * 64 + g * 16) ^ (((row >> 1) & 7) << 4));
        ah[mi] = *(const f16x8*)((const char*)h_s + byte);
      }
      #pragma unroll
      for (int ni = 0; ni < 4; ni++) {
        int rw = wc * 64 + ni * 16 + fr;       // d row (0..127)
        int byte = rw * 128 + ((ks * 64 + g * 16) ^ (((rw >> 1) & 7) << 4));
        bq[ni] = *(const f16x8*)((const char*)Wb2 + byte);
      }
      #pragma unroll
      for (int mi = 0; mi < 2; mi++)
        #pragma unroll
        for (int ni = 0; ni < 4; ni++)
          acc2[mi][ni] = __builtin_amdgcn_mfma_f32_16x16x32_f16(ah[mi], bq[ni], acc2[mi][ni], 0, 0, 0);
    }
    __syncthreads();                   // next W1 ready; h_s safe to overwrite
  }
  // epilogue: gate-scale + fp16 scatter to slots
  #pragma unroll
  for (int mi = 0; mi < 2; mi++)
    #pragma unroll
    for (int ni = 0; ni < 4; ni++) {
      int ncol = wc * 64 + ni * 16 + fr;
      #pragma unroll
      for (int r = 0; r < 4; r++) {
        int m = wr * 32 + mi * 16 + g * 4 + r;
        int a = alist[m];
        if (a >= 0)
          slots[(size_t)a * HD + ncol] = (_Float16)(aw[m] * (acc2[mi][ni][r] + b2v[ni]));
      }
    }
}

// combine slots -> momentum update -> residual -> LayerNorm; writes nm_out (fp32) + out_h (fp16)
// 1 wave per token (2 elems/lane), 4 tokens/block
__global__ __launch_bounds__(256) void combine_ln_kernel(
    const _Float16* __restrict__ slots, const float* __restrict__ momentum,
    const _Float16* __restrict__ t_h, const float* __restrict__ ln_g, const float* __restrict__ ln_b,
    float* __restrict__ nm_out, _Float16* __restrict__ out_h) {
  int w = threadIdx.x >> 6, lane = threadIdx.x & 63;
  int tok = blockIdx.x * 4 + w;
  int d0 = lane * 2;
  f16x2 s0 = *(const f16x2*)(slots + (size_t)tok * 256 + d0);
  f16x2 s1 = *(const f16x2*)(slots + (size_t)tok * 256 + 128 + d0);
  float2 mo = *(const float2*)(momentum + (size_t)tok * HD + d0);
  f16x2 tv = *(const f16x2*)(t_h + (size_t)tok * HD + d0);
  float nm0 = -((float)s0.x + (float)s1.x) + MU_F * mo.x;
  float nm1 = -((float)s0.y + (float)s1.y) + MU_F * mo.y;
  float2 nm2; nm2.x = nm0; nm2.y = nm1;
  *(float2*)(nm_out + (size_t)tok * HD + d0) = nm2;
  float r0 = (float)tv.x + nm0;
  float r1 = (float)tv.y + nm1;
  float s = r0 + r1, sq = r0 * r0 + r1 * r1;
  #pragma unroll
  for (int m = 1; m < 64; m <<= 1) { s += __shfl_xor(s, m, 64); sq += __shfl_xor(sq, m, 64); }
  float mean = s * (1.f / 128.f);
  float var = sq * (1.f / 128.f) - mean * mean;
  float is = rsqrtf(var + LN_EPS_F);
  float y0 = (r0 - mean) * is * ln_g[d0] + ln_b[d0];
  float y1 = (r1 - mean) * is * ln_g[d0 + 1] + ln_b[d0 + 1];
  f16x2 yo = { (_Float16)y0, (_Float16)y1 };
  *(f16x2*)(out_h + (size_t)tok * HD + d0) = yo;
}

extern "C" void kernel_launch(void* const* d_in, const int* in_sizes, int n_in,
                              void* d_out, int out_size, void* d_ws, size_t ws_size,
                              hipStream_t stream) {
  const float* x        = (const float*)d_in[0];
  const float* momentum = (const float*)d_in[1];
  const float* split_W  = (const float*)d_in[2];
  const float* split_b  = (const float*)d_in[3];
  const float* gate_W   = (const float*)d_in[4];
  const float* gate_b   = (const float*)d_in[5];
  const float* W1       = (const float*)d_in[6];
  const float* b1       = (const float*)d_in[7];
  const float* W2       = (const float*)d_in[8];
  const float* b2       = (const float*)d_in[9];
  const float* ln_g     = (const float*)d_in[10];
  const float* ln_b     = (const float*)d_in[11];
  const float* merge_W  = (const float*)d_in[12];
  const float* merge_b  = (const float*)d_in[13];
  float* final_out = (float*)d_out;
  float* nm_out    = final_out + (size_t)NBS * ND;

  char* ws = (char*)d_ws;
  size_t off = 0;
  auto alloc = [&](size_t bytes) { void* p = ws + off; off = (off + bytes + 255) & ~(size_t)255; return p; };
  _Float16* x_h   = (_Float16*)alloc((size_t)NBS * ND * 2);
  _Float16* t_h   = (_Float16*)alloc((size_t)NT * HD * 2);
  _Float16* out_h = (_Float16*)alloc((size_t)NT * HD * 2);
  _Float16* sWt   = (_Float16*)alloc((size_t)ND * ND * 2);
  _Float16* mWt   = (_Float16*)alloc((size_t)ND * ND * 2);
  _Float16* W1t   = (_Float16*)alloc((size_t)NE * HD * NFF * 2);
  _Float16* W2t   = (_Float16*)alloc((size_t)NE * HD * NFF * 2);
  f64x2*    Gx2   = (f64x2*)alloc((size_t)512 * 64 * 16);
  double*   gbias = (double*)alloc(64 * 8);
  float*    tkw   = (float*)alloc((size_t)NT * 2 * 4);
  int*      lists = (int*)alloc((size_t)NE * NT * 4);
  int*      cnt   = (int*)alloc(512 * 4);
  _Float16* slots = (_Float16*)alloc((size_t)NT * 2 * HD * 2);
  (void)in_sizes; (void)n_in; (void)out_size; (void)ws_size;

  zero_cnt_kernel<<<1, 512, 0, stream>>>(cnt);
  tr_cvt_kernel<<<dim3(32, 32, 1), dim3(32, 8), 0, stream>>>(split_W, sWt, ND, ND);
  tr_cvt_kernel<<<dim3(32, 32, 1), dim3(32, 8), 0, stream>>>(merge_W, mWt, ND, ND);
  tr_cvt_kernel<<<dim3(16, 4, 8), dim3(32, 8), 0, stream>>>(W1, W1t, HD, NFF);
  tr_cvt_kernel<<<dim3(4, 16, 8), dim3(32, 8), 0, stream>>>(W2, W2t, NFF, HD);
  build_G_kernel<<<128, 256, 0, stream>>>(split_W, split_b, gate_W, gate_b, Gx2, gbias);
  // gate also produces x_h (fused convert), so it runs before the split GEMM
  gate_kernel<<<512, 256, 0, stream>>>(x, Gx2, gbias, x_h, tkw, lists, cnt);
  // t = x @ split_W + split_b   (fp16 out for downstream MFMA)
  gemm_f16_kernel<<<dim3(8, 64), 256, 0, stream>>>(x_h, sWt, split_b, nullptr, t_h, NBS, ND, ND);
  expert_kernel<<<NE * 512, 512, 0, stream>>>(t_h, W1t, W2t, b1, b2, cnt, lists, tkw, slots);
  combine_ln_kernel<<<NT / 4, 256, 0, stream>>>(slots, momentum, t_h, ln_g, ln_b, nm_out, out_h);
  // final = out @ merge_W + merge_b
  gemm_f16_kernel<<<dim3(8, 64), 256, 0, stream>>>(out_h, mWt, merge_b, final_out, nullptr, NBS, ND, ND);
}

// Round 10
// 247.815 us; speedup vs baseline: 1.5387x; 1.0121x over previous
//
#include <hip/hip_runtime.h>

#define NBATCH 4
#define NS 2048
#define ND 1024
#define NH 8
#define HD 128
#define NFF 512
#define NE 8
#define NT 65536       /* B*S*H tokens */
#define NBS 8192       /* B*S rows */
#define MU_F 0.7f
#define LN_EPS_F 1e-5f

typedef __attribute__((ext_vector_type(4))) float f32x4;
typedef __attribute__((ext_vector_type(2))) double f64x2;
typedef __attribute__((ext_vector_type(8))) _Float16 f16x8;
typedef __attribute__((ext_vector_type(4))) _Float16 f16x4;
typedef __attribute__((ext_vector_type(2))) _Float16 f16x2;

__device__ __forceinline__ void gload_lds16(const void* g, void* l) {
  __builtin_amdgcn_global_load_lds(
      (const __attribute__((address_space(1))) unsigned int*)g,
      (__attribute__((address_space(3))) unsigned int*)l, 16, 0, 0);
}

// cnt is strided: cnt[e*64] so the 8 counters live in different cache lines/TCC channels
__global__ void zero_cnt_kernel(int* cnt) {
  cnt[threadIdx.x] = 0;
}

// batched transpose + convert: in [batch][R][C] f32 -> out [batch][C][R] f16
// R, C multiples of 32. block (32,8), grid (C/32, R/32, batch)
__global__ void tr_cvt_kernel(const float* __restrict__ in, _Float16* __restrict__ out, int R, int C) {
  __shared__ float tile[32][33];
  int b = blockIdx.z;
  const float* inp = in + (size_t)b * R * C;
  _Float16* outp = out + (size_t)b * R * C;
  int c = blockIdx.x * 32 + threadIdx.x;
  int r0 = blockIdx.y * 32;
  #pragma unroll
  for (int i = 0; i < 4; i++) {
    int r = r0 + threadIdx.y + i * 8;
    tile[threadIdx.y + i * 8][threadIdx.x] = inp[(size_t)r * C + c];
  }
  __syncthreads();
  int rr = r0 + threadIdx.x;
  #pragma unroll
  for (int i = 0; i < 4; i++) {
    int cc = blockIdx.x * 32 + threadIdx.y + i * 8;
    outp[(size_t)cc * R + rr] = (_Float16)tile[threadIdx.x][threadIdx.y + i * 8];
  }
}

// Gx2[kp*64 + o] = { G[2kp][o], G[2kp+1][o] } (fp64), o = h*8+e
__global__ void build_G_kernel(const float* __restrict__ split_W, const float* __restrict__ split_b,
                               const float* __restrict__ gate_W, const float* __restrict__ gate_b,
                               f64x2* __restrict__ Gx2, double* __restrict__ gbias) {
  int idx = blockIdx.x * 256 + threadIdx.x;   // kp*64 + o, 32768 total
  int kp = idx >> 6, o = idx & 63, h = o >> 3, e = o & 7;
  int d0 = kp * 2;
  double a0 = 0.0, a1 = 0.0;
  const float* r0 = split_W + (size_t)d0 * ND + h * 128;
  const float* r1 = r0 + ND;
  for (int j = 0; j < 128; j++) {
    double w = (double)gate_W[j * 8 + e];
    a0 += (double)r0[j] * w;
    a1 += (double)r1[j] * w;
  }
  f64x2 gv = { a0, a1 };
  Gx2[idx] = gv;
  if (idx < 64) {
    double bacc = 0.0;
    for (int j = 0; j < 128; j++)
      bacc += (double)split_b[h * 128 + j] * (double)gate_W[j * 8 + e];
    gbias[idx] = bacc + (double)gate_b[e];
  }
}

// fp64 logits = x @ G + gbias, top-2 per (row,h), softmax, per-expert lists.
// v5: G read directly from global (coalesced, L2-resident); x staged in LDS;
// fused x->fp16; hierarchical atomics.
__global__ __launch_bounds__(256) void gate_kernel(const float* __restrict__ x,
    const f64x2* __restrict__ Gx2, const double* __restrict__ gbias,
    _Float16* __restrict__ x_h,
    float* __restrict__ tkw, int* __restrict__ lists, int* __restrict__ cnt) {
  __shared__ double xsd[16][66];     // 8.25 KB
  __shared__ double lg[16 * 64];     // 8 KB
  __shared__ int lcnt[8];
  __shared__ int lbase[8];
  int tid = threadIdx.x, lane = tid & 63, w = tid >> 6;
  int bs0 = blockIdx.x * 16;
  double acc[4];
  #pragma unroll
  for (int r = 0; r < 4; r++) acc[r] = 0.0;
  int xrow = tid >> 4, xc4 = tid & 15;
  const double* xr = &xsd[0][0] + (w * 4) * 66;
  if (tid < 8) lcnt[tid] = 0;

  for (int ch = 0; ch < 16; ch++) {
    __syncthreads();           // previous chunk's reads complete before overwrite
    float4 xv4 = *(const float4*)(x + (size_t)(bs0 + xrow) * ND + ch * 64 + xc4 * 4);
    f64x2 xa = { (double)xv4.x, (double)xv4.y };
    f64x2 xb = { (double)xv4.z, (double)xv4.w };
    *(f64x2*)&xsd[xrow][xc4 * 4]     = xa;
    *(f64x2*)&xsd[xrow][xc4 * 4 + 2] = xb;
    // fused fp16 conversion of x (replaces cvt kernel)
    f16x4 xh = { (_Float16)xv4.x, (_Float16)xv4.y, (_Float16)xv4.z, (_Float16)xv4.w };
    *(f16x4*)(x_h + (size_t)(bs0 + xrow) * ND + ch * 64 + xc4 * 4) = xh;
    __syncthreads();
    const f64x2* Gc = Gx2 + (size_t)(ch * 32) * 64 + lane;
    #pragma unroll 8
    for (int kp = 0; kp < 32; kp++) {
      f64x2 g = Gc[kp * 64];               // global, coalesced 1KB/wave, L2-hit
      #pragma unroll
      for (int r = 0; r < 4; r++) {
        f64x2 xv = *(const f64x2*)(xr + r * 66 + kp * 2);   // LDS broadcast
        acc[r] += xv.x * g.x;
        acc[r] += xv.y * g.y;
      }
    }
  }
  double gb = gbias[lane];
  #pragma unroll
  for (int r = 0; r < 4; r++)
    lg[(w * 4 + r) * 64 + lane] = acc[r] + gb;
  __syncthreads();

  int i1 = 0, i2 = 0, token = 0, p1 = 0, p2 = 0;
  if (tid < 128) {
    int row = tid >> 3, h = tid & 7;
    const double* L = lg + row * 64 + h * 8;
    double v1 = L[0];
    #pragma unroll
    for (int e2 = 1; e2 < 8; e2++) if (L[e2] > v1) { v1 = L[e2]; i1 = e2; }
    i2 = -1; double v2 = -1e300;
    #pragma unroll
    for (int e2 = 0; e2 < 8; e2++) if (e2 != i1 && L[e2] > v2) { v2 = L[e2]; i2 = e2; }
    float ex = expf((float)(v2 - v1));        // <= 1
    float den = 1.f + ex;
    float g1 = 1.f / den, g2 = ex / den;
    token = (bs0 + row) * 8 + h;
    tkw[token * 2]     = g1;
    tkw[token * 2 + 1] = g2;
    p1 = atomicAdd(&lcnt[i1], 1);             // LDS atomics: cheap
    p2 = atomicAdd(&lcnt[i2], 1);
  }
  __syncthreads();
  if (tid < 8) lbase[tid] = atomicAdd(cnt + tid * 64, lcnt[tid]);   // 8 global atomics/block
  __syncthreads();
  if (tid < 128) {
    lists[(size_t)i1 * NT + lbase[i1] + p1] = token * 2;
    lists[(size_t)i2 * NT + lbase[i2] + p2] = token * 2 + 1;
  }
}

// C[M][N] = A[M][K] @ Bt[N][K]^T + bias; fp16 inputs, fp32 acc.
// 128x128 tile, BK=32, 4 waves (2x2 of 64x64), global_load_lds width 16.
__global__ __launch_bounds__(256) void gemm_f16_kernel(
    const _Float16* __restrict__ A, const _Float16* __restrict__ Bt,
    const float* __restrict__ bias, float* __restrict__ Cf, _Float16* __restrict__ Ch,
    int M, int N, int Kd) {
  __shared__ _Float16 As[128 * 32];
  __shared__ _Float16 Bs[128 * 32];
  int tid = threadIdx.x, lane = tid & 63, w = tid >> 6;
  int wr = w >> 1, wc = w & 1;
  int m0 = blockIdx.y * 128, n0 = blockIdx.x * 128;
  f32x4 acc[4][4];
  #pragma unroll
  for (int i = 0; i < 4; i++)
    #pragma unroll
    for (int j = 0; j < 4; j++) acc[i][j] = (f32x4){0.f, 0.f, 0.f, 0.f};
  int srow = lane >> 2, scol = (lane & 3) * 8;
  int fr = lane & 15, ko = (lane >> 4) * 8;
  const _Float16* Ag = A + (size_t)(m0 + srow) * Kd + scol;
  const _Float16* Bg = Bt + (size_t)(n0 + srow) * Kd + scol;

  for (int k0 = 0; k0 < Kd; k0 += 32) {
    #pragma unroll
    for (int j = 0; j < 2; j++) {
      int rb = (w * 2 + j) * 16;
      gload_lds16(Ag + (size_t)rb * Kd + k0, As + rb * 32);
      gload_lds16(Bg + (size_t)rb * Kd + k0, Bs + rb * 32);
    }
    __syncthreads();
    f16x8 af[4], bq[4];
    #pragma unroll
    for (int mi = 0; mi < 4; mi++) af[mi] = *(const f16x8*)(As + (wr * 64 + mi * 16 + fr) * 32 + ko);
    #pragma unroll
    for (int ni = 0; ni < 4; ni++) bq[ni] = *(const f16x8*)(Bs + (wc * 64 + ni * 16 + fr) * 32 + ko);
    __syncthreads();
    #pragma unroll
    for (int mi = 0; mi < 4; mi++)
      #pragma unroll
      for (int ni = 0; ni < 4; ni++)
        acc[mi][ni] = __builtin_amdgcn_mfma_f32_16x16x32_f16(af[mi], bq[ni], acc[mi][ni], 0, 0, 0);
  }
  int rbase = m0 + wr * 64 + ((lane >> 4) << 2);
  int cbase = n0 + wc * 64 + (lane & 15);
  #pragma unroll
  for (int mi = 0; mi < 4; mi++)
    #pragma unroll
    for (int ni = 0; ni < 4; ni++) {
      int cc = cbase + ni * 16;
      float bv = bias ? bias[cc] : 0.f;
      #pragma unroll
      for (int r = 0; r < 4; r++) {
        int rr = rbase + mi * 16 + r;
        float v = acc[mi][ni][r] + bv;
        if (Cf) Cf[(size_t)rr * N + cc] = v;
        if (Ch) Ch[(size_t)rr * N + cc] = (_Float16)v;
      }
    }
}

// Grouped expert kernel v7: COUNTED-VMCNT RING PIPELINE (guide T3/T4).
// 16 phases (8 ch x {W1,W2}); 3-buffer 16KB ring staged 2 phases ahead via
// global_load_lds; per-phase sync = s_waitcnt vmcnt(2) + raw s_barrier (never
// drain to 0 in the loop -- v6's __syncthreads emitted vmcnt(0), serializing
// every phase on staging latency). b1/b2 moved to LDS in prologue so the ONLY
// vmcnt events in the loop are the stage loads (deterministic counts).
// Ring-reuse safety: stage(p+2) targets ring[(p+2)%3], whose last reader
// (phase p-1) passed the barrier that opened phase p.
// LDS 67.5 KB + VGPR<=128 -> 2 blocks/CU. Swizzle as v6.
__global__ __launch_bounds__(512, 2) void expert_kernel(
    const _Float16* __restrict__ t_h, const _Float16* __restrict__ W1t, const _Float16* __restrict__ W2t,
    const float* __restrict__ b1, const float* __restrict__ b2,
    const int* __restrict__ cnt, const int* __restrict__ lists, const float* __restrict__ tkw,
    _Float16* __restrict__ slots) {
  int e = blockIdx.x & 7;              // consecutive blocks -> different XCDs
  int m0 = (blockIdx.x >> 3) * 128;
  int count = cnt[e * 64];
  if (m0 >= count) return;
  __shared__ _Float16 ring[3][64 * 128];  // 3 x 16 KB staging ring
  __shared__ _Float16 h_s[128 * 64];      // 16 KB [tok128][ff64] 128B rows
  __shared__ float b1s[NFF];              // 2 KB
  __shared__ float b2s[HD];               // 512 B
  __shared__ int alist[128];
  __shared__ float aw[128];
  int tid = threadIdx.x, lane = tid & 63, w = tid >> 6;
  int wr = w >> 1, wc = w & 1;         // 4 row-quarters (32) x 2 col-halves (64)
  int fr = lane & 15, g = lane >> 4;

  if (tid < 128) {
    int idx = m0 + tid;
    int a = (idx < count) ? lists[(size_t)e * NT + idx] : -1;
    alist[tid] = a;
    aw[tid] = (a >= 0) ? tkw[a] : 0.f;
  }
  b1s[tid] = b1[e * NFF + tid];
  if (tid < 128) b2s[tid] = b2[e * HD + tid];
  __syncthreads();

  // stage phase p's weights into ring[p%3]. p even: W1 chunk (64 ff rows x 128 d);
  // p odd: W2 chunk (128 d rows x 64 ff). Source pre-swizzled: sg = gg^((r>>1)&7).
  auto stage = [&](int p) {
    if (p >= 16) return;
    int ch = p >> 1;
    _Float16* dst = &ring[p % 3][0];
    if ((p & 1) == 0) {
      #pragma unroll
      for (int j = 0; j < 2; j++) {
        int n = j * 512 + tid;           // 16 granules per 256B row
        int r = n >> 4, gg = n & 15;
        int sg = gg ^ ((r >> 1) & 7);
        gload_lds16(W1t + (size_t)e * (NFF * HD) + (size_t)(ch * 64 + r) * HD + sg * 8, dst + n * 8);
      }
    } else {
      #pragma unroll
      for (int j = 0; j < 2; j++) {
        int n = j * 512 + tid;           // 8 granules per 128B row
        int r = n >> 3, gg = n & 7;
        int sg = gg ^ ((r >> 1) & 7);
        gload_lds16(W2t + (size_t)e * (HD * NFF) + (size_t)r * NFF + ch * 64 + sg * 8, dst + n * 8);
      }
    }
  };

  // gather this wave's 32 token rows into registers (held across all phases)
  f16x8 af[2][4];
  #pragma unroll
  for (int mi = 0; mi < 2; mi++) {
    int rloc = wr * 32 + mi * 16 + fr;
    int a = alist[rloc];
    const _Float16* tb = t_h + (size_t)(a >> 1) * HD;
    #pragma unroll
    for (int ks = 0; ks < 4; ks++) {
      f16x8 v = {0, 0, 0, 0, 0, 0, 0, 0};
      if (a >= 0) v = *(const f16x8*)(tb + ks * 32 + g * 8);
      af[mi][ks] = v;
    }
  }
  asm volatile("s_waitcnt vmcnt(0)" ::: "memory");   // drain gather: loop vmcnt is stage-only
  stage(0); stage(1);
  asm volatile("s_waitcnt vmcnt(2) lgkmcnt(0)\n\ts_barrier" ::: "memory");  // stage(0) landed everywhere

  f32x4 acc2[2][4];
  #pragma unroll
  for (int i = 0; i < 2; i++)
    #pragma unroll
    for (int j = 0; j < 4; j++) acc2[i][j] = (f32x4){0.f, 0.f, 0.f, 0.f};

  #pragma unroll
  for (int p = 0; p < 16; p++) {
    stage(p + 2);
    int ch = p >> 1;
    const char* WB = (const char*)&ring[p % 3][0];
    if ((p & 1) == 0) {
      // ---- A: h(:, ch*64..) = relu(t @ W1chunk + b1) ----
      float b1v[2];
      #pragma unroll
      for (int ni = 0; ni < 2; ni++)
        b1v[ni] = b1s[ch * 64 + wc * 32 + ni * 16 + fr];
      f32x4 acc1[2][2];
      #pragma unroll
      for (int i = 0; i < 2; i++)
        #pragma unroll
        for (int j = 0; j < 2; j++) acc1[i][j] = (f32x4){0.f, 0.f, 0.f, 0.f};
      #pragma unroll
      for (int ks = 0; ks < 4; ks++) {
        f16x8 bq[2];
        #pragma unroll
        for (int ni = 0; ni < 2; ni++) {
          int rw = wc * 32 + ni * 16 + fr;       // ff row of chunk (0..63)
          int byte = rw * 256 + ((ks * 64 + g * 16) ^ (((rw >> 1) & 7) << 4));
          bq[ni] = *(const f16x8*)(WB + byte);
        }
        #pragma unroll
        for (int mi = 0; mi < 2; mi++)
          #pragma unroll
          for (int ni = 0; ni < 2; ni++)
            acc1[mi][ni] = __builtin_amdgcn_mfma_f32_16x16x32_f16(af[mi][ks], bq[ni], acc1[mi][ni], 0, 0, 0);
      }
      #pragma unroll
      for (int mi = 0; mi < 2; mi++)
        #pragma unroll
        for (int ni = 0; ni < 2; ni++) {
          int hc = wc * 32 + ni * 16 + fr;
          #pragma unroll
          for (int r = 0; r < 4; r++) {
            int hr = wr * 32 + mi * 16 + g * 4 + r;
            int byte = hr * 128 + ((hc * 2) ^ (((hr >> 1) & 7) << 4));
            *(_Float16*)((char*)h_s + byte) = (_Float16)fmaxf(acc1[mi][ni][r] + b1v[ni], 0.f);
          }
        }
    } else {
      // ---- B: acc2 += h(:, ch) @ W2chunk ----
      #pragma unroll
      for (int ks = 0; ks < 2; ks++) {
        f16x8 ah[2], bq[4];
        #pragma unroll
        for (int mi = 0; mi < 2; mi++) {
          int row = wr * 32 + mi * 16 + fr;
          int byte = row * 128 + ((ks * 64 + g * 16) ^ (((row >> 1) & 7) << 4));
          ah[mi] = *(const f16x8*)((const char*)h_s + byte);
        }
        #pragma unroll
        for (int ni = 0; ni < 4; ni++) {
          int rw = wc * 64 + ni * 16 + fr;       // d row (0..127)
          int byte = rw * 128 + ((ks * 64 + g * 16) ^ (((rw >> 1) & 7) << 4));
          bq[ni] = *(const f16x8*)((const char*)&ring[p % 3][0] + byte);
        }
        #pragma unroll
        for (int mi = 0; mi < 2; mi++)
          #pragma unroll
          for (int ni = 0; ni < 4; ni++)
            acc2[mi][ni] = __builtin_amdgcn_mfma_f32_16x16x32_f16(ah[mi], bq[ni], acc2[mi][ni], 0, 0, 0);
      }
    }
    // phase sync: next phase's weights landed (counted), h_s coherent.
    if (p == 14) {
      asm volatile("s_waitcnt vmcnt(0) lgkmcnt(0)\n\ts_barrier" ::: "memory");
    } else if (p < 14) {
      asm volatile("s_waitcnt vmcnt(2) lgkmcnt(0)\n\ts_barrier" ::: "memory");
    }
  }
  // epilogue: gate-scale + fp16 scatter to slots
  #pragma unroll
  for (int mi = 0; mi < 2; mi++)
    #pragma unroll
    for (int ni = 0; ni < 4; ni++) {
      int ncol = wc * 64 + ni * 16 + fr;
      float bv = b2s[ncol];
      #pragma unroll
      for (int r = 0; r < 4; r++) {
        int m = wr * 32 + mi * 16 + g * 4 + r;
        int a = alist[m];
        if (a >= 0)
          slots[(size_t)a * HD + ncol] = (_Float16)(aw[m] * (acc2[mi][ni][r] + bv));
      }
    }
}

// combine slots -> momentum update -> residual -> LayerNorm; writes nm_out (fp32) + out_h (fp16)
// 1 wave per token (2 elems/lane), 4 tokens/block
__global__ __launch_bounds__(256) void combine_ln_kernel(
    const _Float16* __restrict__ slots, const float* __restrict__ momentum,
    const _Float16* __restrict__ t_h, const float* __restrict__ ln_g, const float* __restrict__ ln_b,
    float* __restrict__ nm_out, _Float16* __restrict__ out_h) {
  int w = threadIdx.x >> 6, lane = threadIdx.x & 63;
  int tok = blockIdx.x * 4 + w;
  int d0 = lane * 2;
  f16x2 s0 = *(const f16x2*)(slots + (size_t)tok * 256 + d0);
  f16x2 s1 = *(const f16x2*)(slots + (size_t)tok * 256 + 128 + d0);
  float2 mo = *(const float2*)(momentum + (size_t)tok * HD + d0);
  f16x2 tv = *(const f16x2*)(t_h + (size_t)tok * HD + d0);
  float nm0 = -((float)s0.x + (float)s1.x) + MU_F * mo.x;
  float nm1 = -((float)s0.y + (float)s1.y) + MU_F * mo.y;
  float2 nm2; nm2.x = nm0; nm2.y = nm1;
  *(float2*)(nm_out + (size_t)tok * HD + d0) = nm2;
  float r0 = (float)tv.x + nm0;
  float r1 = (float)tv.y + nm1;
  float s = r0 + r1, sq = r0 * r0 + r1 * r1;
  #pragma unroll
  for (int m = 1; m < 64; m <<= 1) { s += __shfl_xor(s, m, 64); sq += __shfl_xor(sq, m, 64); }
  float mean = s * (1.f / 128.f);
  float var = sq * (1.f / 128.f) - mean * mean;
  float is = rsqrtf(var + LN_EPS_F);
  float y0 = (r0 - mean) * is * ln_g[d0] + ln_b[d0];
  float y1 = (r1 - mean) * is * ln_g[d0 + 1] + ln_b[d0 + 1];
  f16x2 yo = { (_Float16)y0, (_Float16)y1 };
  *(f16x2*)(out_h + (size_t)tok * HD + d0) = yo;
}

extern "C" void kernel_launch(void* const* d_in, const int* in_sizes, int n_in,
                              void* d_out, int out_size, void* d_ws, size_t ws_size,
                              hipStream_t stream) {
  const float* x        = (const float*)d_in[0];
  const float* momentum = (const float*)d_in[1];
  const float* split_W  = (const float*)d_in[2];
  const float* split_b  = (const float*)d_in[3];
  const float* gate_W   = (const float*)d_in[4];
  const float* gate_b   = (const float*)d_in[5];
  const float* W1       = (const float*)d_in[6];
  const float* b1       = (const float*)d_in[7];
  const float* W2       = (const float*)d_in[8];
  const float* b2       = (const float*)d_in[9];
  const float* ln_g     = (const float*)d_in[10];
  const float* ln_b     = (const float*)d_in[11];
  const float* merge_W  = (const float*)d_in[12];
  const float* merge_b  = (const float*)d_in[13];
  float* final_out = (float*)d_out;
  float* nm_out    = final_out + (size_t)NBS * ND;

  char* ws = (char*)d_ws;
  size_t off = 0;
  auto alloc = [&](size_t bytes) { void* p = ws + off; off = (off + bytes + 255) & ~(size_t)255; return p; };
  _Float16* x_h   = (_Float16*)alloc((size_t)NBS * ND * 2);
  _Float16* t_h   = (_Float16*)alloc((size_t)NT * HD * 2);
  _Float16* out_h = (_Float16*)alloc((size_t)NT * HD * 2);
  _Float16* sWt   = (_Float16*)alloc((size_t)ND * ND * 2);
  _Float16* mWt   = (_Float16*)alloc((size_t)ND * ND * 2);
  _Float16* W1t   = (_Float16*)alloc((size_t)NE * HD * NFF * 2);
  _Float16* W2t   = (_Float16*)alloc((size_t)NE * HD * NFF * 2);
  f64x2*    Gx2   = (f64x2*)alloc((size_t)512 * 64 * 16);
  double*   gbias = (double*)alloc(64 * 8);
  float*    tkw   = (float*)alloc((size_t)NT * 2 * 4);
  int*      lists = (int*)alloc((size_t)NE * NT * 4);
  int*      cnt   = (int*)alloc(512 * 4);
  _Float16* slots = (_Float16*)alloc((size_t)NT * 2 * HD * 2);
  (void)in_sizes; (void)n_in; (void)out_size; (void)ws_size;

  zero_cnt_kernel<<<1, 512, 0, stream>>>(cnt);
  tr_cvt_kernel<<<dim3(32, 32, 1), dim3(32, 8), 0, stream>>>(split_W, sWt, ND, ND);
  tr_cvt_kernel<<<dim3(32, 32, 1), dim3(32, 8), 0, stream>>>(merge_W, mWt, ND, ND);
  tr_cvt_kernel<<<dim3(16, 4, 8), dim3(32, 8), 0, stream>>>(W1, W1t, HD, NFF);
  tr_cvt_kernel<<<dim3(4, 16, 8), dim3(32, 8), 0, stream>>>(W2, W2t, NFF, HD);
  build_G_kernel<<<128, 256, 0, stream>>>(split_W, split_b, gate_W, gate_b, Gx2, gbias);
  // gate also produces x_h (fused convert), so it runs before the split GEMM
  gate_kernel<<<512, 256, 0, stream>>>(x, Gx2, gbias, x_h, tkw, lists, cnt);
  // t = x @ split_W + split_b   (fp16 out for downstream MFMA)
  gemm_f16_kernel<<<dim3(8, 64), 256, 0, stream>>>(x_h, sWt, split_b, nullptr, t_h, NBS, ND, ND);
  expert_kernel<<<NE * 512, 512, 0, stream>>>(t_h, W1t, W2t, b1, b2, cnt, lists, tkw, slots);
  combine_ln_kernel<<<NT / 4, 256, 0, stream>>>(slots, momentum, t_h, ln_g, ln_b, nm_out, out_h);
  // final = out @ merge_W + merge_b
  gemm_f16_kernel<<<dim3(8, 64), 256, 0, stream>>>(out_h, mWt, merge_b, final_out, nullptr, NBS, ND, ND);
}